// Round 12
// baseline (671.604 us; speedup 1.0000x reference)
//
#include <hip/hip_runtime.h>

// Vector Quantizer, MFMA split-bf16 path + exact fp32 refine (row-major Et).
// inputs  d_in[0]: float32 X [32768, 256]
// emb     d_in[1]: float32 E [256, 4096]
// d_out: [8388608 floats e_k] + [1 float loss]
//
// dot(x,e) ~ 3 bf16 MFMAs: xh*eh + xh*el + xl*eh (fp32 accum).
// dist_mfma v13 = R9 structure (A+B LDS, 2x32KB dbuf, stage-before-compute)
// with m4n4 wave decomposition: 4 waves in a 2x2 grid, each wave owns
// 64 rows x 64 cols (m=4, n=4 16x16 blocks). Reuse bound 1/m+1/n = 0.5
// (vs 0.625 at R9's m2n8): per-wave LDS frag reads drop 320->256 B/lane/kt.
// acc stays 64 regs (no R10 register cliff). Since 2 waves share rows,
// top-2 is kept per (strip, col-half): 16 slots x 2 = 32 cands/row (ushort),
// race-free writes; refine checks all 32 with exact fp32.
// Xh/Xl bf16 (row-major) staged in d_out (overwritten by gather later).

typedef unsigned short ushort_t;
typedef unsigned int uint_t;
typedef __attribute__((ext_vector_type(8))) short bf16x8;
typedef __attribute__((ext_vector_type(4))) float f32x4;

#define N_ROWS 32768
#define DIM 256
#define K_CODES 4096
#define NKS 8            // col strips (512 cols each)
#define GATHER_BLOCKS 512
#define RG_BLOCKS (N_ROWS / 32)   // fused refine+gather: 32 rows/block

// ---- ws layout (mfma path), bytes ----
// Ehi      [0,       2097152)   bf16 [4096][256]   (dead after dist_mfma)
// Elo      [2097152, 4194304)                      (dead after dist_mfma)
// Et       [0,       4194304)   fp32 [4096][256]   (built after dist_mfma)
// cand     [4194304, 6291456)   ushort [32768][16 slots][2]
// esq      [6291456, 6307840)   float[4096]
// partials [6438912, 6443008)   float[1024]
#define WS_NEEDED (8u * 1024u * 1024u)

__device__ __forceinline__ unsigned short bf16_rne(float x) {
    unsigned u = __builtin_bit_cast(unsigned, x);
    unsigned r = u + 0x7fffu + ((u >> 16) & 1u);
    return (unsigned short)(r >> 16);
}
__device__ __forceinline__ float bf16_f(unsigned short h) {
    unsigned u = ((unsigned)h) << 16;
    return __builtin_bit_cast(float, u);
}
// total-order "better": smaller dist, tie -> smaller index
__device__ __forceinline__ bool better(float d, int c, float v, int i) {
    return (d < v) || (d == v && c < i);
}

// ---------------- prep: X -> Xh/Xl (bf16 split, row-major), into d_out -----
__global__ void prep_x(const float* __restrict__ X, ushort_t* __restrict__ Xh,
                       ushort_t* __restrict__ Xl) {
    int i = blockIdx.x * 256 + threadIdx.x;   // float4 index
    float4 v = ((const float4*)X)[i];
    ushort4 h, l;
    h.x = bf16_rne(v.x); l.x = bf16_rne(v.x - bf16_f(h.x));
    h.y = bf16_rne(v.y); l.y = bf16_rne(v.y - bf16_f(h.y));
    h.z = bf16_rne(v.z); l.z = bf16_rne(v.z - bf16_f(h.z));
    h.w = bf16_rne(v.w); l.w = bf16_rne(v.w - bf16_f(h.w));
    ((ushort4*)Xh)[i] = h;
    ((ushort4*)Xl)[i] = l;
}

// ------------- prep: E [256][4096] -> E^T hi/lo [4096][256] bf16 -----------
__global__ void prep_e(const float* __restrict__ E, ushort_t* __restrict__ Ehi,
                       ushort_t* __restrict__ Elo) {
    __shared__ ushort_t sh[64][66];
    __shared__ ushort_t sl[64][66];
    const int t = threadIdx.x;
    const int kbase = blockIdx.x * 64;
    const int dbase = blockIdx.y * 64;
#pragma unroll
    for (int i = 0; i < 16; ++i) {
        int lin = i * 256 + t;
        int dl = lin >> 6, kl = lin & 63;
        float v = E[(size_t)(dbase + dl) * K_CODES + kbase + kl];
        unsigned short h = bf16_rne(v);
        unsigned short l = bf16_rne(v - bf16_f(h));
        sh[kl][dl] = h;
        sl[kl][dl] = l;
    }
    __syncthreads();
#pragma unroll
    for (int i = 0; i < 8; ++i) {
        int lin = i * 256 + t;
        int kl = lin >> 5, d2 = (lin & 31) * 2;
        uint_t vh = (uint_t)sh[kl][d2] | ((uint_t)sh[kl][d2 + 1] << 16);
        uint_t vl = (uint_t)sl[kl][d2] | ((uint_t)sl[kl][d2 + 1] << 16);
        *(uint_t*)&Ehi[(size_t)(kbase + kl) * DIM + dbase + d2] = vh;
        *(uint_t*)&Elo[(size_t)(kbase + kl) * DIM + dbase + d2] = vl;
    }
}

// ------------- prep: E [256][4096] -> Et fp32 [4096][256] (exact) ----------
__global__ void prep_et(const float* __restrict__ E, float* __restrict__ Et) {
    __shared__ float s[64][65];
    const int t = threadIdx.x;
    const int kbase = blockIdx.x * 64;
    const int dbase = blockIdx.y * 64;
#pragma unroll
    for (int i = 0; i < 16; ++i) {
        int lin = i * 256 + t;
        int dl = lin >> 6, kl = lin & 63;
        s[kl][dl] = E[(size_t)(dbase + dl) * K_CODES + kbase + kl];
    }
    __syncthreads();
#pragma unroll
    for (int i = 0; i < 16; ++i) {
        int lin = i * 256 + t;
        int kl = lin >> 6, dl = lin & 63;
        Et[(size_t)(kbase + kl) * DIM + dbase + dl] = s[kl][dl];
    }
}

// ---------------- esq[k] = sum_d E[d][k]^2 (fp32, from original E) ---------
__global__ void esq_kernel(const float* __restrict__ E, float* __restrict__ esq) {
    __shared__ float red[16][17];
    int t = threadIdx.x;
    int kk = t & 15, dg = t >> 4;
    int k = blockIdx.x * 16 + kk;
    float a = 0.f;
#pragma unroll
    for (int it = 0; it < 16; ++it) {
        float e = E[(dg + it * 16) * K_CODES + k];
        a = fmaf(e, e, a);
    }
    red[dg][kk] = a;
    __syncthreads();
    if (t < 16) {
        float s = 0.f;
#pragma unroll
        for (int g = 0; g < 16; ++g) s += red[g][t];
        esq[blockIdx.x * 16 + t] = s;
    }
}

// ---------------- main: MFMA distance + per-(strip,half) top-2 (v13) -------
// grid (NKS, 256) flattened+swizzled: xcd = wgid%8 owns rowblocks
// [xcd*32, xcd*32+32) x all strips; within XCD, strip varies fastest.
// 256 threads = 4 waves in 2x2: wave (wr,wc) owns rows [wr*64, wr*64+64)
// (m=4 blocks) x cols [wc*64, wc*64+64) of each 128-col ct (n=4 blocks).
// A+B staged to LDS per kt (32 KB), double-buffered (2x32 KB), stage of
// step s+1 issued BEFORE compute of step s (identical staging to R9).
// LDS buf p at p*16384 shorts: A_hi +0, A_lo +4096, B_hi +8192, B_lo +12288;
// each region = [8 blocks of 16][64 lanes][8 bf16] (fragment-packed).
__global__ void __launch_bounds__(256) dist_mfma(
    const ushort_t* __restrict__ Xh, const ushort_t* __restrict__ Xl,
    const ushort_t* __restrict__ Ehi, const ushort_t* __restrict__ Elo,
    const float* __restrict__ esq, ushort_t* __restrict__ cand) {
    __shared__ short lds[32768];   // 64 KB, two 32 KB buffers
    const int t = threadIdx.x;
    const int l = t & 63, w = t >> 6;
    const int l15 = l & 15, lg = l >> 4;
    const int wr = w >> 1, wc = w & 1;

    // bijective XCD swizzle (2048 blocks = 8 XCD x 256)
    const int wgid = blockIdx.x + blockIdx.y * NKS;
    const int xcd = wgid & 7, pos = wgid >> 3;
    const int ks = pos & 7;
    const int rowbase = (xcd * 32 + (pos >> 3)) * 128;

    const int ab0 = 2 * w, ab1 = 2 * w + 1;   // blocks staged by this wave

#define GLDS(srcp, dstoff)                                                      \
    __builtin_amdgcn_global_load_lds(                                           \
        (const __attribute__((address_space(1))) void*)(srcp),                  \
        (__attribute__((address_space(3))) void*)&lds[dstoff], 16, 0, 0)
#define STAGE(pbuf, cbase, ktv) do {                                            \
    const uint_t ao0 = (uint_t)(rowbase + ab0 * 16 + l15) * DIM + (ktv) * 32 + lg * 8; \
    const uint_t ao1 = (uint_t)(rowbase + ab1 * 16 + l15) * DIM + (ktv) * 32 + lg * 8; \
    const uint_t bo0 = (uint_t)((cbase) + ab0 * 16 + l15) * DIM + (ktv) * 32 + lg * 8; \
    const uint_t bo1 = (uint_t)((cbase) + ab1 * 16 + l15) * DIM + (ktv) * 32 + lg * 8; \
    GLDS(Xh  + ao0, (pbuf) * 16384 +         ab0 * 512);                        \
    GLDS(Xh  + ao1, (pbuf) * 16384 +         ab1 * 512);                        \
    GLDS(Xl  + ao0, (pbuf) * 16384 +  4096 + ab0 * 512);                        \
    GLDS(Xl  + ao1, (pbuf) * 16384 +  4096 + ab1 * 512);                        \
    GLDS(Ehi + bo0, (pbuf) * 16384 +  8192 + ab0 * 512);                        \
    GLDS(Ehi + bo1, (pbuf) * 16384 +  8192 + ab1 * 512);                        \
    GLDS(Elo + bo0, (pbuf) * 16384 + 12288 + ab0 * 512);                        \
    GLDS(Elo + bo1, (pbuf) * 16384 + 12288 + ab1 * 512);                        \
} while (0)

    float v1[4][4], v2[4][4];
    int   i1[4][4], i2[4][4];
#pragma unroll
    for (int m = 0; m < 4; ++m)
#pragma unroll
        for (int q = 0; q < 4; ++q) {
            v1[m][q] = 3.4e38f; v2[m][q] = 3.4e38f;
            i1[m][q] = 0x7fffffff; i2[m][q] = 0x7fffffff;
        }

    // prologue: stage (ct=0, kt=0) into buf 0, wait for it
    STAGE(0, ks * 512, 0);
    __syncthreads();

#pragma unroll 1
    for (int ct = 0; ct < 4; ++ct) {
        const int cb = ks * 512 + ct * 128;

        f32x4 acc[4][4];
#pragma unroll
        for (int m = 0; m < 4; ++m)
#pragma unroll
            for (int n = 0; n < 4; ++n) acc[m][n] = (f32x4){0.f, 0.f, 0.f, 0.f};

#pragma unroll
        for (int kt = 0; kt < 8; ++kt) {
            const int cur = kt & 1;
            // stage next step into the other buffer BEFORE compute
            if (kt < 7) {
                STAGE(cur ^ 1, cb, kt + 1);
            } else if (ct < 3) {
                STAGE(cur ^ 1, cb + 128, 0);
            }
            // compute current step from buf[cur]: wave (wr,wc) reads its
            // 4 A-blocks and 4 B-blocks only (m4n4 reuse)
            bf16x8 ah[4], al[4];
#pragma unroll
            for (int m = 0; m < 4; ++m) {
                ah[m] = *(const bf16x8*)&lds[cur * 16384 + (wr * 4 + m) * 512 + l * 8];
                al[m] = *(const bf16x8*)&lds[cur * 16384 + 4096 + (wr * 4 + m) * 512 + l * 8];
            }
#pragma unroll
            for (int n = 0; n < 4; ++n) {
                const bf16x8 bh = *(const bf16x8*)&lds[cur * 16384 + 8192 + (wc * 4 + n) * 512 + l * 8];
                const bf16x8 bl = *(const bf16x8*)&lds[cur * 16384 + 12288 + (wc * 4 + n) * 512 + l * 8];
#pragma unroll
                for (int m = 0; m < 4; ++m) {
                    acc[m][n] = __builtin_amdgcn_mfma_f32_16x16x32_bf16(
                        ah[m], bh, acc[m][n], 0, 0, 0);
                    acc[m][n] = __builtin_amdgcn_mfma_f32_16x16x32_bf16(
                        ah[m], bl, acc[m][n], 0, 0, 0);
                    acc[m][n] = __builtin_amdgcn_mfma_f32_16x16x32_bf16(
                        al[m], bh, acc[m][n], 0, 0, 0);
                }
            }
            // barrier: drains vmcnt (next stage, issued ~460 MFMA-cyc ago)
            __syncthreads();
        }

        // epilogue: dist = esq - 2*dot, top-2 update per (m,q)
#pragma unroll
        for (int n = 0; n < 4; ++n) {
            const int col = cb + (wc * 4 + n) * 16 + l15;
            const float eq = esq[col];
#pragma unroll
            for (int m = 0; m < 4; ++m)
#pragma unroll
                for (int q = 0; q < 4; ++q) {
                    const float d = fmaf(-2.f, acc[m][n][q], eq);
                    if (better(d, col, v1[m][q], i1[m][q])) {
                        v2[m][q] = v1[m][q]; i2[m][q] = i1[m][q];
                        v1[m][q] = d;        i1[m][q] = col;
                    } else if (better(d, col, v2[m][q], i2[m][q])) {
                        v2[m][q] = d; i2[m][q] = col;
                    }
                }
        }
    }
#undef STAGE
#undef GLDS

    // cross-lane top-2 merge over the 16 col-lanes (indices all distinct).
    // Writer (l15==0) covers rows rowbase + wr*64 + m*16 + lg*4 + q;
    // slot = ks*2 + wc -> unique (row, slot) per writer: race-free.
#pragma unroll
    for (int m = 0; m < 4; ++m)
#pragma unroll
        for (int q = 0; q < 4; ++q) {
            float a1 = v1[m][q], a2 = v2[m][q];
            int   b1 = i1[m][q], b2 = i2[m][q];
#pragma unroll
            for (int msk = 8; msk >= 1; msk >>= 1) {
                const float c1 = __shfl_xor(a1, msk, 64);
                const int   d1 = __shfl_xor(b1, msk, 64);
                const float c2 = __shfl_xor(a2, msk, 64);
                const int   d2 = __shfl_xor(b2, msk, 64);
                if (better(c1, d1, a1, b1)) {
                    if (better(a1, b1, c2, d2)) { a2 = a1; b2 = b1; }
                    else                        { a2 = c2; b2 = d2; }
                    a1 = c1; b1 = d1;
                } else {
                    if (better(c1, d1, a2, b2)) { a2 = c1; b2 = d1; }
                }
            }
            if (l15 == 0) {
                const int row = rowbase + wr * 64 + m * 16 + lg * 4 + q;
                ushort2 c2v;
                c2v.x = (ushort_t)b1;
                c2v.y = (ushort_t)b2;
                *(ushort2*)&cand[(size_t)row * 32 + (ks * 2 + wc) * 2] = c2v;
            }
        }
}

// ------- fused refine (exact fp32 over 32 cands) + gather + loss -----------
// 4 waves/block, 8 rows each. Refine: lane = (cand 0..31) x (half 0..1 of
// 128 dims); xor-32 sum, then xor-16..1 argmin -> ALL lanes hold the winner.
__global__ void refine_gather(const float* __restrict__ X, const float* __restrict__ Et,
                              const ushort_t* __restrict__ cand,
                              float* __restrict__ out, float* __restrict__ partials) {
    const int w = threadIdx.x >> 6, l = threadIdx.x & 63;
    const int cs = l & 31, dg = l >> 5;
    const int row0 = blockIdx.x * 32 + w * 8;
    float lsum = 0.f;

#pragma unroll 1
    for (int rr = 0; rr < 8; ++rr) {
        const int row = row0 + rr;
        const int c = (int)cand[(size_t)row * 32 + cs];
        const float4* ep = (const float4*)(Et + (size_t)c * DIM + dg * 128);
        const float4* xp = (const float4*)(X + (size_t)row * DIM + dg * 128);
        float p = 0.f;
#pragma unroll 8
        for (int j = 0; j < 32; ++j) {
            const float4 e = ep[j];
            const float4 x = xp[j];
            p = fmaf(e.x, fmaf(-2.f, x.x, e.x), p);
            p = fmaf(e.y, fmaf(-2.f, x.y, e.y), p);
            p = fmaf(e.z, fmaf(-2.f, x.z, e.z), p);
            p = fmaf(e.w, fmaf(-2.f, x.w, e.w), p);
        }
        p += __shfl_xor(p, 32, 64);
        float v = p; int id = c;
#pragma unroll
        for (int m = 16; m >= 1; m >>= 1) {
            const float v2 = __shfl_xor(v, m, 64);
            const int  id2 = __shfl_xor(id, m, 64);
            if (v2 < v || (v2 == v && id2 < id)) { v = v2; id = id2; }
        }
        // gather + loss (all lanes agree on id)
        const float4 x = *(const float4*)(X + (size_t)row * DIM + l * 4);
        const float4 q = *(const float4*)(Et + (size_t)id * DIM + l * 4);
        *(float4*)(out + (size_t)row * DIM + l * 4) = q;
        const float d0 = x.x - q.x, d1 = x.y - q.y, d2 = x.z - q.z, d3 = x.w - q.w;
        lsum += d0 * d0 + d1 * d1 + d2 * d2 + d3 * d3;
    }
#pragma unroll
    for (int m = 32; m >= 1; m >>= 1) lsum += __shfl_xor(lsum, m, 64);
    __shared__ float ws4[4];
    if (l == 0) ws4[w] = lsum;
    __syncthreads();
    if (threadIdx.x == 0) partials[blockIdx.x] = (ws4[0] + ws4[1]) + (ws4[2] + ws4[3]);
}

// -------- fallback fp32 dist (round-1 proven path, used if ws too small) ---
__global__ void dist_fp32(const float* __restrict__ X, const float* __restrict__ E,
                          const float* __restrict__ esq,
                          float* __restrict__ candv, int* __restrict__ candi) {
    __shared__ float Xs[8][128];
    __shared__ float Es[8][128];
    const int t = threadIdx.x;
    const int tx = t & 15;
    const int ty = t >> 4;
    const int rowbase = blockIdx.x * 128;
    const int ks = blockIdx.y;

    float minv[8];
    int   mini[8];
#pragma unroll
    for (int i = 0; i < 8; ++i) { minv[i] = 3.4e38f; mini[i] = 0; }

    for (int kt = 0; kt < 8; ++kt) {
        const int kbase = ks * 1024 + kt * 128;
        float acc[8][8];
#pragma unroll
        for (int i = 0; i < 8; ++i)
#pragma unroll
            for (int j = 0; j < 8; ++j) acc[i][j] = 0.f;

        for (int dc = 0; dc < DIM / 8; ++dc) {
            const int d0 = dc * 8;
            {
                const int row = t >> 1;
                const int dsl = (t & 1) * 4;
                const float4 xv = *(const float4*)(X + (size_t)(rowbase + row) * DIM + d0 + dsl);
                Xs[dsl + 0][row] = xv.x; Xs[dsl + 1][row] = xv.y;
                Xs[dsl + 2][row] = xv.z; Xs[dsl + 3][row] = xv.w;
            }
            {
                const int dr = t >> 5;
                const int c4 = (t & 31) * 4;
                const float4 ev = *(const float4*)(E + (size_t)(d0 + dr) * K_CODES + kbase + c4);
                *(float4*)&Es[dr][c4] = ev;
            }
            __syncthreads();
#pragma unroll
            for (int d = 0; d < 8; ++d) {
                float xr[8], er[8];
                *(float4*)&xr[0] = *(const float4*)&Xs[d][ty * 8];
                *(float4*)&xr[4] = *(const float4*)&Xs[d][ty * 8 + 4];
                *(float4*)&er[0] = *(const float4*)&Es[d][tx * 8];
                *(float4*)&er[4] = *(const float4*)&Es[d][tx * 8 + 4];
#pragma unroll
                for (int i = 0; i < 8; ++i)
#pragma unroll
                    for (int j = 0; j < 8; ++j)
                        acc[i][j] = fmaf(xr[i], er[j], acc[i][j]);
            }
            __syncthreads();
        }
        float eq[8];
        *(float4*)&eq[0] = *(const float4*)(esq + kbase + tx * 8);
        *(float4*)&eq[4] = *(const float4*)(esq + kbase + tx * 8 + 4);
#pragma unroll
        for (int i = 0; i < 8; ++i)
#pragma unroll
            for (int j = 0; j < 8; ++j) {
                const float dist = fmaf(-2.f, acc[i][j], eq[j]);
                if (dist < minv[i]) { minv[i] = dist; mini[i] = kbase + tx * 8 + j; }
            }
    }
#pragma unroll
    for (int i = 0; i < 8; ++i) {
        float v = minv[i];
        int   id = mini[i];
#pragma unroll
        for (int m = 8; m >= 1; m >>= 1) {
            const float v2 = __shfl_xor(v, m, 64);
            const int   i2 = __shfl_xor(id, m, 64);
            if (v2 < v || (v2 == v && i2 < id)) { v = v2; id = i2; }
        }
        if (tx == 0) {
            const int row = rowbase + ty * 8 + i;
            candv[row * 4 + ks] = v;
            candi[row * 4 + ks] = id;
        }
    }
}

__global__ void gather_loss(const float* __restrict__ X, const float* __restrict__ E,
                            const float* __restrict__ candv, const int* __restrict__ candi,
                            float* __restrict__ out, float* __restrict__ partials,
                            int nks) {
    const int w = threadIdx.x >> 6;
    const int l = threadIdx.x & 63;
    const int rowbase = blockIdx.x * (N_ROWS / GATHER_BLOCKS);
    float lsum = 0.f;

    for (int rr = w; rr < N_ROWS / GATHER_BLOCKS; rr += 4) {
        const int row = rowbase + rr;
        float bv = candv[row * nks];
        int   bi = candi[row * nks];
        for (int s = 1; s < nks; ++s) {
            const float v = candv[row * nks + s];
            const int  id = candi[row * nks + s];
            if (v < bv || (v == bv && id < bi)) { bv = v; bi = id; }
        }
        const float4 x = *(const float4*)(X + (size_t)row * DIM + l * 4);
        const float q0 = E[(size_t)(l * 4 + 0) * K_CODES + bi];
        const float q1 = E[(size_t)(l * 4 + 1) * K_CODES + bi];
        const float q2 = E[(size_t)(l * 4 + 2) * K_CODES + bi];
        const float q3 = E[(size_t)(l * 4 + 3) * K_CODES + bi];
        float4 q; q.x = q0; q.y = q1; q.z = q2; q.w = q3;
        *(float4*)(out + (size_t)row * DIM + l * 4) = q;
        const float d0 = x.x - q0, d1 = x.y - q1, d2 = x.z - q2, d3 = x.w - q3;
        lsum += d0 * d0 + d1 * d1 + d2 * d2 + d3 * d3;
    }
#pragma unroll
    for (int m = 32; m >= 1; m >>= 1) lsum += __shfl_xor(lsum, m, 64);
    __shared__ float ws4[4];
    if (l == 0) ws4[w] = lsum;
    __syncthreads();
    if (threadIdx.x == 0) partials[blockIdx.x] = (ws4[0] + ws4[1]) + (ws4[2] + ws4[3]);
}

__global__ void finalize(const float* __restrict__ partials, float* __restrict__ out_loss,
                         int npart) {
    __shared__ double s[256];
    double a = 0.0;
    for (int i = threadIdx.x; i < npart; i += 256) a += (double)partials[i];
    s[threadIdx.x] = a;
    __syncthreads();
    for (int st = 128; st > 0; st >>= 1) {
        if (threadIdx.x < st) s[threadIdx.x] += s[threadIdx.x + st];
        __syncthreads();
    }
    if (threadIdx.x == 0)
        out_loss[0] = (float)(1.25 * s[0] / (double)(N_ROWS * DIM));
}

extern "C" void kernel_launch(void* const* d_in, const int* in_sizes, int n_in,
                              void* d_out, int out_size, void* d_ws, size_t ws_size,
                              hipStream_t stream) {
    const float* X = (const float*)d_in[0];
    const float* E = (const float*)d_in[1];
    float* out = (float*)d_out;

    if (ws_size >= (size_t)WS_NEEDED) {
        // ---------------- MFMA path ----------------
        ushort_t* Ehi      = (ushort_t*)((char*)d_ws + 0);
        ushort_t* Elo      = (ushort_t*)((char*)d_ws + 2097152);
        float*    Et       = (float*)   ((char*)d_ws + 0);        // after dist_mfma
        ushort_t* cand     = (ushort_t*)((char*)d_ws + 4194304);  // 2 MB
        float*    esq      = (float*)   ((char*)d_ws + 6291456);
        float*    partials = (float*)   ((char*)d_ws + 6438912);
        ushort_t* Xh       = (ushort_t*)d_out;                    // 16.78 MB
        ushort_t* Xl       = Xh + (size_t)N_ROWS * DIM;           // 16.78 MB

        prep_x<<<(N_ROWS * DIM / 4) / 256, 256, 0, stream>>>(X, Xh, Xl);
        prep_e<<<dim3(K_CODES / 64, DIM / 64), 256, 0, stream>>>(E, Ehi, Elo);
        esq_kernel<<<K_CODES / 16, 256, 0, stream>>>(E, esq);
        dist_mfma<<<dim3(NKS, N_ROWS / 128), 256, 0, stream>>>(
            Xh, Xl, Ehi, Elo, esq, cand);
        prep_et<<<dim3(K_CODES / 64, DIM / 64), 256, 0, stream>>>(E, Et);
        refine_gather<<<RG_BLOCKS, 256, 0, stream>>>(X, Et, cand, out, partials);
        finalize<<<1, 256, 0, stream>>>(partials, out + (size_t)N_ROWS * DIM, RG_BLOCKS);
    } else {
        // ---------------- fallback: round-1 fp32 path (needs ~1.07 MB) -----
        float* esq      = (float*)((char*)d_ws + 0);
        float* candv    = (float*)((char*)d_ws + 16384);
        int*   candi    = (int*)  ((char*)d_ws + 540672);
        float* partials = (float*)((char*)d_ws + 1064960);

        esq_kernel<<<K_CODES / 16, 256, 0, stream>>>(E, esq);
        dist_fp32<<<dim3(N_ROWS / 128, 4), 256, 0, stream>>>(X, E, esq, candv, candi);
        gather_loss<<<GATHER_BLOCKS, 256, 0, stream>>>(X, E, candv, candi, out,
                                                       partials, 4);
        finalize<<<1, 256, 0, stream>>>(partials, out + (size_t)N_ROWS * DIM,
                                        GATHER_BLOCKS);
    }
}

// Round 13
// 358.401 us; speedup vs baseline: 1.8739x; 1.8739x over previous
//
#include <hip/hip_runtime.h>

// Vector Quantizer, MFMA split-bf16 path + exact fp32 refine (row-major Et).
// inputs  d_in[0]: float32 X [32768, 256]
// emb     d_in[1]: float32 E [256, 4096]
// d_out: [8388608 floats e_k] + [1 float loss]
//
// dot(x,e) ~ 3 bf16 MFMAs: xh*eh + xh*el + xl*eh (fp32 accum).
// dist_mfma v14 = R5/R6's A-register-file structure (fastest measured dist,
// 335 us) with NKS 8->4: strips of 1024 cols, 1024 blocks, ct-loop x8.
// The A-file (128 VGPRs; spills ~50 regs under the 128-cap) now amortizes
// over 2x the compute -> spill traffic and A re-fetch halve per FLOP.
// Top-2 per (row, 1024-col strip) -> 8 cands/row -> exact fp32 refine.
// Xh/Xl bf16 (row-major) staged in d_out (overwritten by gather later).

typedef unsigned short ushort_t;
typedef unsigned int uint_t;
typedef __attribute__((ext_vector_type(8))) short bf16x8;
typedef __attribute__((ext_vector_type(4))) float f32x4;

#define N_ROWS 32768
#define DIM 256
#define K_CODES 4096
#define NKS 4            // col strips (1024 cols each)
#define GATHER_BLOCKS 512
#define RG_BLOCKS (N_ROWS / 32)   // fused refine+gather: 32 rows/block

// ---- ws layout (mfma path), bytes ----
// Ehi      [0,       2097152)   bf16 [4096][256]   (dead after dist_mfma)
// Elo      [2097152, 4194304)                      (dead after dist_mfma)
// Et       [0,       4194304)   fp32 [4096][256]   (built after dist_mfma)
// cand     [4194304, 5242880)   int [32768][4 strips][2]
// esq      [6291456, 6307840)   float[4096]
// partials [6438912, 6443008)   float[1024]
#define WS_NEEDED (8u * 1024u * 1024u)

__device__ __forceinline__ unsigned short bf16_rne(float x) {
    unsigned u = __builtin_bit_cast(unsigned, x);
    unsigned r = u + 0x7fffu + ((u >> 16) & 1u);
    return (unsigned short)(r >> 16);
}
__device__ __forceinline__ float bf16_f(unsigned short h) {
    unsigned u = ((unsigned)h) << 16;
    return __builtin_bit_cast(float, u);
}
// total-order "better": smaller dist, tie -> smaller index
__device__ __forceinline__ bool better(float d, int c, float v, int i) {
    return (d < v) || (d == v && c < i);
}

// ---------------- prep: X -> Xh/Xl (bf16 split, row-major), into d_out -----
__global__ void prep_x(const float* __restrict__ X, ushort_t* __restrict__ Xh,
                       ushort_t* __restrict__ Xl) {
    int i = blockIdx.x * 256 + threadIdx.x;   // float4 index
    float4 v = ((const float4*)X)[i];
    ushort4 h, l;
    h.x = bf16_rne(v.x); l.x = bf16_rne(v.x - bf16_f(h.x));
    h.y = bf16_rne(v.y); l.y = bf16_rne(v.y - bf16_f(h.y));
    h.z = bf16_rne(v.z); l.z = bf16_rne(v.z - bf16_f(h.z));
    h.w = bf16_rne(v.w); l.w = bf16_rne(v.w - bf16_f(h.w));
    ((ushort4*)Xh)[i] = h;
    ((ushort4*)Xl)[i] = l;
}

// ------------- prep: E [256][4096] -> E^T hi/lo [4096][256] bf16 -----------
__global__ void prep_e(const float* __restrict__ E, ushort_t* __restrict__ Ehi,
                       ushort_t* __restrict__ Elo) {
    __shared__ ushort_t sh[64][66];
    __shared__ ushort_t sl[64][66];
    const int t = threadIdx.x;
    const int kbase = blockIdx.x * 64;
    const int dbase = blockIdx.y * 64;
#pragma unroll
    for (int i = 0; i < 16; ++i) {
        int lin = i * 256 + t;
        int dl = lin >> 6, kl = lin & 63;
        float v = E[(size_t)(dbase + dl) * K_CODES + kbase + kl];
        unsigned short h = bf16_rne(v);
        unsigned short l = bf16_rne(v - bf16_f(h));
        sh[kl][dl] = h;
        sl[kl][dl] = l;
    }
    __syncthreads();
#pragma unroll
    for (int i = 0; i < 8; ++i) {
        int lin = i * 256 + t;
        int kl = lin >> 5, d2 = (lin & 31) * 2;
        uint_t vh = (uint_t)sh[kl][d2] | ((uint_t)sh[kl][d2 + 1] << 16);
        uint_t vl = (uint_t)sl[kl][d2] | ((uint_t)sl[kl][d2 + 1] << 16);
        *(uint_t*)&Ehi[(size_t)(kbase + kl) * DIM + dbase + d2] = vh;
        *(uint_t*)&Elo[(size_t)(kbase + kl) * DIM + dbase + d2] = vl;
    }
}

// ------------- prep: E [256][4096] -> Et fp32 [4096][256] (exact) ----------
__global__ void prep_et(const float* __restrict__ E, float* __restrict__ Et) {
    __shared__ float s[64][65];
    const int t = threadIdx.x;
    const int kbase = blockIdx.x * 64;
    const int dbase = blockIdx.y * 64;
#pragma unroll
    for (int i = 0; i < 16; ++i) {
        int lin = i * 256 + t;
        int dl = lin >> 6, kl = lin & 63;
        s[kl][dl] = E[(size_t)(dbase + dl) * K_CODES + kbase + kl];
    }
    __syncthreads();
#pragma unroll
    for (int i = 0; i < 16; ++i) {
        int lin = i * 256 + t;
        int kl = lin >> 6, dl = lin & 63;
        Et[(size_t)(kbase + kl) * DIM + dbase + dl] = s[kl][dl];
    }
}

// ---------------- esq[k] = sum_d E[d][k]^2 (fp32, from original E) ---------
__global__ void esq_kernel(const float* __restrict__ E, float* __restrict__ esq) {
    __shared__ float red[16][17];
    int t = threadIdx.x;
    int kk = t & 15, dg = t >> 4;
    int k = blockIdx.x * 16 + kk;
    float a = 0.f;
#pragma unroll
    for (int it = 0; it < 16; ++it) {
        float e = E[(dg + it * 16) * K_CODES + k];
        a = fmaf(e, e, a);
    }
    red[dg][kk] = a;
    __syncthreads();
    if (t < 16) {
        float s = 0.f;
#pragma unroll
        for (int g = 0; g < 16; ++g) s += red[g][t];
        esq[blockIdx.x * 16 + t] = s;
    }
}

// ---------------- main: MFMA distance + per-strip top-2 (v14) --------------
// grid (NKS=4, 256) flattened+swizzled: 1024 = 8 xcd x 128; xcd owns 32
// contiguous rowblocks x all 4 strips. 256 threads = 4 waves; wave w owns
// rows [w*32, w*32+32) (2 m-blocks) x all 128 cols of each ct tile.
// A (X hi/lo) fragments in registers (loaded once, 128 VGPRs; ~50 spill to
// L2-backed scratch under the 128-cap -- amortized over 8 ct iterations);
// B (E^T hi/lo) staged to LDS double-buffered, 16 KB per kt step, stage
// issued before compute.
__global__ void __launch_bounds__(256, 2) dist_mfma(
    const ushort_t* __restrict__ Xh, const ushort_t* __restrict__ Xl,
    const ushort_t* __restrict__ Ehi, const ushort_t* __restrict__ Elo,
    const float* __restrict__ esq, int* __restrict__ cand) {
    __shared__ short lds[16384];   // 32 KB: buf p at p*8192 shorts,
                                   // within buf: Bh [0,4096) Bl [4096,8192)
    const int t = threadIdx.x;
    const int l = t & 63, w = t >> 6;
    const int l15 = l & 15, lg = l >> 4;

    // bijective XCD swizzle (1024 blocks = 8 XCD x 128)
    const int wgid = blockIdx.x + blockIdx.y * NKS;
    const int xcd = wgid & 7, pos = wgid >> 3;
    const int ks = pos & 3;
    const int rowbase = (xcd * 32 + (pos >> 2)) * 128;

    const int n0 = 2 * w, n1 = 2 * w + 1;   // B n-blocks staged by this wave

#define GLDS(srcp, dstoff)                                                      \
    __builtin_amdgcn_global_load_lds(                                           \
        (const __attribute__((address_space(1))) void*)(srcp),                  \
        (__attribute__((address_space(3))) void*)&lds[dstoff], 16, 0, 0)
#define STAGE(pbuf, cbase, ktv) do {                                            \
    const uint_t o0 = (uint_t)((cbase) + n0 * 16 + l15) * DIM + (ktv) * 32 + lg * 8; \
    const uint_t o1 = (uint_t)((cbase) + n1 * 16 + l15) * DIM + (ktv) * 32 + lg * 8; \
    GLDS(Ehi + o0, (pbuf) * 8192 + n0 * 512);                                   \
    GLDS(Ehi + o1, (pbuf) * 8192 + n1 * 512);                                   \
    GLDS(Elo + o0, (pbuf) * 8192 + 4096 + n0 * 512);                            \
    GLDS(Elo + o1, (pbuf) * 8192 + 4096 + n1 * 512);                            \
} while (0)

    // issue first B-stage before the A prologue so DMA overlaps A latency
    STAGE(0, ks * 1024, 0);

    // ---- A prologue: 2 m-blocks x 8 kt, hi+lo fragments -> 128 VGPRs
    bf16x8 ah[2][8], al[2][8];
#pragma unroll
    for (int m = 0; m < 2; ++m) {
        const uint_t base = (uint_t)(rowbase + w * 32 + m * 16 + l15) * DIM + lg * 8;
#pragma unroll
        for (int kt = 0; kt < 8; ++kt) {
            ah[m][kt] = *(const bf16x8*)(Xh + base + kt * 32);
            al[m][kt] = *(const bf16x8*)(Xl + base + kt * 32);
        }
    }

    float v1[2][4], v2[2][4];
    int   i1[2][4], i2[2][4];
#pragma unroll
    for (int m = 0; m < 2; ++m)
#pragma unroll
        for (int q = 0; q < 4; ++q) {
            v1[m][q] = 3.4e38f; v2[m][q] = 3.4e38f;
            i1[m][q] = 0x7fffffff; i2[m][q] = 0x7fffffff;
        }

    __syncthreads();

#pragma unroll 1
    for (int ct = 0; ct < 8; ++ct) {
        const int cb = ks * 1024 + ct * 128;

        f32x4 acc[2][8];
#pragma unroll
        for (int m = 0; m < 2; ++m)
#pragma unroll
            for (int n = 0; n < 8; ++n) acc[m][n] = (f32x4){0.f, 0.f, 0.f, 0.f};

#pragma unroll
        for (int kt = 0; kt < 8; ++kt) {
            const int cur = kt & 1;
            // stage next (ct,kt) into the other buffer BEFORE compute
            if (kt < 7) {
                STAGE(cur ^ 1, cb, kt + 1);
            } else if (ct < 7) {
                STAGE(cur ^ 1, cb + 128, 0);
            }
            // compute current kt from buf[cur] (A from registers)
#pragma unroll
            for (int n = 0; n < 8; ++n) {
                const bf16x8 bh = *(const bf16x8*)&lds[cur * 8192 + n * 512 + l * 8];
                const bf16x8 bl = *(const bf16x8*)&lds[cur * 8192 + 4096 + n * 512 + l * 8];
#pragma unroll
                for (int m = 0; m < 2; ++m) {
                    acc[m][n] = __builtin_amdgcn_mfma_f32_16x16x32_bf16(
                        ah[m][kt], bh, acc[m][n], 0, 0, 0);
                    acc[m][n] = __builtin_amdgcn_mfma_f32_16x16x32_bf16(
                        ah[m][kt], bl, acc[m][n], 0, 0, 0);
                    acc[m][n] = __builtin_amdgcn_mfma_f32_16x16x32_bf16(
                        al[m][kt], bh, acc[m][n], 0, 0, 0);
                }
            }
            // barrier: drains vmcnt (next stage) + lgkm
            __syncthreads();
        }

        // epilogue: dist = esq - 2*dot, top-2 update per (m,q)
#pragma unroll
        for (int n = 0; n < 8; ++n) {
            const int col = cb + n * 16 + l15;
            const float eq = esq[col];
#pragma unroll
            for (int m = 0; m < 2; ++m)
#pragma unroll
                for (int q = 0; q < 4; ++q) {
                    const float d = fmaf(-2.f, acc[m][n][q], eq);
                    if (better(d, col, v1[m][q], i1[m][q])) {
                        v2[m][q] = v1[m][q]; i2[m][q] = i1[m][q];
                        v1[m][q] = d;        i1[m][q] = col;
                    } else if (better(d, col, v2[m][q], i2[m][q])) {
                        v2[m][q] = d; i2[m][q] = col;
                    }
                }
        }
    }
#undef STAGE
#undef GLDS

    // cross-lane top-2 merge over the 16 col-lanes (indices all distinct)
#pragma unroll
    for (int m = 0; m < 2; ++m)
#pragma unroll
        for (int q = 0; q < 4; ++q) {
            float a1 = v1[m][q], a2 = v2[m][q];
            int   b1 = i1[m][q], b2 = i2[m][q];
#pragma unroll
            for (int msk = 8; msk >= 1; msk >>= 1) {
                const float c1 = __shfl_xor(a1, msk, 64);
                const int   d1 = __shfl_xor(b1, msk, 64);
                const float c2 = __shfl_xor(a2, msk, 64);
                const int   d2 = __shfl_xor(b2, msk, 64);
                if (better(c1, d1, a1, b1)) {
                    if (better(a1, b1, c2, d2)) { a2 = a1; b2 = b1; }
                    else                        { a2 = c2; b2 = d2; }
                    a1 = c1; b1 = d1;
                } else {
                    if (better(c1, d1, a2, b2)) { a2 = c1; b2 = d1; }
                }
            }
            if (l15 == 0) {
                const int row = rowbase + w * 32 + m * 16 + lg * 4 + q;
                cand[(row * NKS + ks) * 2 + 0] = b1;
                cand[(row * NKS + ks) * 2 + 1] = b2;
            }
        }
}

// ------- fused refine (exact fp32 over 8 cands) + gather + loss ------------
// 4 waves/block, 8 rows each. Refine: lane = (cand 0..7) x (dim-group 0..7
// of 32 dims); xor-8/16/32 sum, then xor-4..1 argmin -> ALL lanes agree.
__global__ void refine_gather(const float* __restrict__ X, const float* __restrict__ Et,
                              const int* __restrict__ cand,
                              float* __restrict__ out, float* __restrict__ partials) {
    const int w = threadIdx.x >> 6, l = threadIdx.x & 63;
    const int cs = l & 7, dg = l >> 3;
    const int row0 = blockIdx.x * 32 + w * 8;
    float lsum = 0.f;

#pragma unroll 1
    for (int rr = 0; rr < 8; ++rr) {
        const int row = row0 + rr;
        const int c = cand[row * 8 + cs];
        const float4* ep = (const float4*)(Et + (size_t)c * DIM + dg * 32);
        const float4* xp = (const float4*)(X + (size_t)row * DIM + dg * 32);
        float p = 0.f;
#pragma unroll
        for (int j = 0; j < 8; ++j) {
            const float4 e = ep[j];
            const float4 x = xp[j];
            p = fmaf(e.x, fmaf(-2.f, x.x, e.x), p);
            p = fmaf(e.y, fmaf(-2.f, x.y, e.y), p);
            p = fmaf(e.z, fmaf(-2.f, x.z, e.z), p);
            p = fmaf(e.w, fmaf(-2.f, x.w, e.w), p);
        }
        p += __shfl_xor(p, 8, 64);
        p += __shfl_xor(p, 16, 64);
        p += __shfl_xor(p, 32, 64);
        float v = p; int id = c;
#pragma unroll
        for (int m = 4; m >= 1; m >>= 1) {
            const float v2 = __shfl_xor(v, m, 64);
            const int  id2 = __shfl_xor(id, m, 64);
            if (v2 < v || (v2 == v && id2 < id)) { v = v2; id = id2; }
        }
        // gather + loss (all lanes agree on id)
        const float4 x = *(const float4*)(X + (size_t)row * DIM + l * 4);
        const float4 q = *(const float4*)(Et + (size_t)id * DIM + l * 4);
        *(float4*)(out + (size_t)row * DIM + l * 4) = q;
        const float d0 = x.x - q.x, d1 = x.y - q.y, d2 = x.z - q.z, d3 = x.w - q.w;
        lsum += d0 * d0 + d1 * d1 + d2 * d2 + d3 * d3;
    }
#pragma unroll
    for (int m = 32; m >= 1; m >>= 1) lsum += __shfl_xor(lsum, m, 64);
    __shared__ float ws4[4];
    if (l == 0) ws4[w] = lsum;
    __syncthreads();
    if (threadIdx.x == 0) partials[blockIdx.x] = (ws4[0] + ws4[1]) + (ws4[2] + ws4[3]);
}

// -------- fallback fp32 dist (round-1 proven path, used if ws too small) ---
__global__ void dist_fp32(const float* __restrict__ X, const float* __restrict__ E,
                          const float* __restrict__ esq,
                          float* __restrict__ candv, int* __restrict__ candi) {
    __shared__ float Xs[8][128];
    __shared__ float Es[8][128];
    const int t = threadIdx.x;
    const int tx = t & 15;
    const int ty = t >> 4;
    const int rowbase = blockIdx.x * 128;
    const int ks = blockIdx.y;

    float minv[8];
    int   mini[8];
#pragma unroll
    for (int i = 0; i < 8; ++i) { minv[i] = 3.4e38f; mini[i] = 0; }

    for (int kt = 0; kt < 8; ++kt) {
        const int kbase = ks * 1024 + kt * 128;
        float acc[8][8];
#pragma unroll
        for (int i = 0; i < 8; ++i)
#pragma unroll
            for (int j = 0; j < 8; ++j) acc[i][j] = 0.f;

        for (int dc = 0; dc < DIM / 8; ++dc) {
            const int d0 = dc * 8;
            {
                const int row = t >> 1;
                const int dsl = (t & 1) * 4;
                const float4 xv = *(const float4*)(X + (size_t)(rowbase + row) * DIM + d0 + dsl);
                Xs[dsl + 0][row] = xv.x; Xs[dsl + 1][row] = xv.y;
                Xs[dsl + 2][row] = xv.z; Xs[dsl + 3][row] = xv.w;
            }
            {
                const int dr = t >> 5;
                const int c4 = (t & 31) * 4;
                const float4 ev = *(const float4*)(E + (size_t)(d0 + dr) * K_CODES + kbase + c4);
                *(float4*)&Es[dr][c4] = ev;
            }
            __syncthreads();
#pragma unroll
            for (int d = 0; d < 8; ++d) {
                float xr[8], er[8];
                *(float4*)&xr[0] = *(const float4*)&Xs[d][ty * 8];
                *(float4*)&xr[4] = *(const float4*)&Xs[d][ty * 8 + 4];
                *(float4*)&er[0] = *(const float4*)&Es[d][tx * 8];
                *(float4*)&er[4] = *(const float4*)&Es[d][tx * 8 + 4];
#pragma unroll
                for (int i = 0; i < 8; ++i)
#pragma unroll
                    for (int j = 0; j < 8; ++j)
                        acc[i][j] = fmaf(xr[i], er[j], acc[i][j]);
            }
            __syncthreads();
        }
        float eq[8];
        *(float4*)&eq[0] = *(const float4*)(esq + kbase + tx * 8);
        *(float4*)&eq[4] = *(const float4*)(esq + kbase + tx * 8 + 4);
#pragma unroll
        for (int i = 0; i < 8; ++i)
#pragma unroll
            for (int j = 0; j < 8; ++j) {
                const float dist = fmaf(-2.f, acc[i][j], eq[j]);
                if (dist < minv[i]) { minv[i] = dist; mini[i] = kbase + tx * 8 + j; }
            }
    }
#pragma unroll
    for (int i = 0; i < 8; ++i) {
        float v = minv[i];
        int   id = mini[i];
#pragma unroll
        for (int m = 8; m >= 1; m >>= 1) {
            const float v2 = __shfl_xor(v, m, 64);
            const int   i2 = __shfl_xor(id, m, 64);
            if (v2 < v || (v2 == v && i2 < id)) { v = v2; id = i2; }
        }
        if (tx == 0) {
            const int row = rowbase + ty * 8 + i;
            candv[row * 4 + ks] = v;
            candi[row * 4 + ks] = id;
        }
    }
}

__global__ void gather_loss(const float* __restrict__ X, const float* __restrict__ E,
                            const float* __restrict__ candv, const int* __restrict__ candi,
                            float* __restrict__ out, float* __restrict__ partials,
                            int nks) {
    const int w = threadIdx.x >> 6;
    const int l = threadIdx.x & 63;
    const int rowbase = blockIdx.x * (N_ROWS / GATHER_BLOCKS);
    float lsum = 0.f;

    for (int rr = w; rr < N_ROWS / GATHER_BLOCKS; rr += 4) {
        const int row = rowbase + rr;
        float bv = candv[row * nks];
        int   bi = candi[row * nks];
        for (int s = 1; s < nks; ++s) {
            const float v = candv[row * nks + s];
            const int  id = candi[row * nks + s];
            if (v < bv || (v == bv && id < bi)) { bv = v; bi = id; }
        }
        const float4 x = *(const float4*)(X + (size_t)row * DIM + l * 4);
        const float q0 = E[(size_t)(l * 4 + 0) * K_CODES + bi];
        const float q1 = E[(size_t)(l * 4 + 1) * K_CODES + bi];
        const float q2 = E[(size_t)(l * 4 + 2) * K_CODES + bi];
        const float q3 = E[(size_t)(l * 4 + 3) * K_CODES + bi];
        float4 q; q.x = q0; q.y = q1; q.z = q2; q.w = q3;
        *(float4*)(out + (size_t)row * DIM + l * 4) = q;
        const float d0 = x.x - q0, d1 = x.y - q1, d2 = x.z - q2, d3 = x.w - q3;
        lsum += d0 * d0 + d1 * d1 + d2 * d2 + d3 * d3;
    }
#pragma unroll
    for (int m = 32; m >= 1; m >>= 1) lsum += __shfl_xor(lsum, m, 64);
    __shared__ float ws4[4];
    if (l == 0) ws4[w] = lsum;
    __syncthreads();
    if (threadIdx.x == 0) partials[blockIdx.x] = (ws4[0] + ws4[1]) + (ws4[2] + ws4[3]);
}

__global__ void finalize(const float* __restrict__ partials, float* __restrict__ out_loss,
                         int npart) {
    __shared__ double s[256];
    double a = 0.0;
    for (int i = threadIdx.x; i < npart; i += 256) a += (double)partials[i];
    s[threadIdx.x] = a;
    __syncthreads();
    for (int st = 128; st > 0; st >>= 1) {
        if (threadIdx.x < st) s[threadIdx.x] += s[threadIdx.x + st];
        __syncthreads();
    }
    if (threadIdx.x == 0)
        out_loss[0] = (float)(1.25 * s[0] / (double)(N_ROWS * DIM));
}

extern "C" void kernel_launch(void* const* d_in, const int* in_sizes, int n_in,
                              void* d_out, int out_size, void* d_ws, size_t ws_size,
                              hipStream_t stream) {
    const float* X = (const float*)d_in[0];
    const float* E = (const float*)d_in[1];
    float* out = (float*)d_out;

    if (ws_size >= (size_t)WS_NEEDED) {
        // ---------------- MFMA path ----------------
        ushort_t* Ehi      = (ushort_t*)((char*)d_ws + 0);
        ushort_t* Elo      = (ushort_t*)((char*)d_ws + 2097152);
        float*    Et       = (float*)   ((char*)d_ws + 0);        // after dist_mfma
        int*      cand     = (int*)     ((char*)d_ws + 4194304);  // 1 MB
        float*    esq      = (float*)   ((char*)d_ws + 6291456);
        float*    partials = (float*)   ((char*)d_ws + 6438912);
        ushort_t* Xh       = (ushort_t*)d_out;                    // 16.78 MB
        ushort_t* Xl       = Xh + (size_t)N_ROWS * DIM;           // 16.78 MB

        prep_x<<<(N_ROWS * DIM / 4) / 256, 256, 0, stream>>>(X, Xh, Xl);
        prep_e<<<dim3(K_CODES / 64, DIM / 64), 256, 0, stream>>>(E, Ehi, Elo);
        esq_kernel<<<K_CODES / 16, 256, 0, stream>>>(E, esq);
        dist_mfma<<<dim3(NKS, N_ROWS / 128), 256, 0, stream>>>(
            Xh, Xl, Ehi, Elo, esq, cand);
        prep_et<<<dim3(K_CODES / 64, DIM / 64), 256, 0, stream>>>(E, Et);
        refine_gather<<<RG_BLOCKS, 256, 0, stream>>>(X, Et, cand, out, partials);
        finalize<<<1, 256, 0, stream>>>(partials, out + (size_t)N_ROWS * DIM, RG_BLOCKS);
    } else {
        // ---------------- fallback: round-1 fp32 path (needs ~1.07 MB) -----
        float* esq      = (float*)((char*)d_ws + 0);
        float* candv    = (float*)((char*)d_ws + 16384);
        int*   candi    = (int*)  ((char*)d_ws + 540672);
        float* partials = (float*)((char*)d_ws + 1064960);

        esq_kernel<<<K_CODES / 16, 256, 0, stream>>>(E, esq);
        dist_fp32<<<dim3(N_ROWS / 128, 4), 256, 0, stream>>>(X, E, esq, candv, candi);
        gather_loss<<<GATHER_BLOCKS, 256, 0, stream>>>(X, E, candv, candi, out,
                                                       partials, 4);
        finalize<<<1, 256, 0, stream>>>(partials, out + (size_t)N_ROWS * DIM,
                                        GATHER_BLOCKS);
    }
}

// Round 14
// 317.495 us; speedup vs baseline: 2.1153x; 1.1288x over previous
//
#include <hip/hip_runtime.h>

// Vector Quantizer, MFMA split-bf16 path + exact fp32 refine (row-major Et).
// inputs  d_in[0]: float32 X [32768, 256]
// emb     d_in[1]: float32 E [256, 4096]
// d_out: [8388608 floats e_k] + [1 float loss]
//
// dot(x,e) ~ 3 bf16 MFMAs: xh*eh + xh*el + xl*eh (fp32 accum).
// dist_mfma v15 = v14 with NKS 4->2: strips of 2048 cols, 512 blocks
// (8 XCD x 64, fully co-resident at 2 blocks/CU), ct-loop x16. The A-file
// (128 VGPRs; ~50 spill under the 128-cap) amortizes over 2x more compute
// again -- v14 (NKS 8->4) measured 335->314 us via exactly this lever.
// Top-2 per (row, 2048-col strip) -> 4 cands/row -> exact fp32 refine.
// Xh/Xl bf16 (row-major) staged in d_out (overwritten by gather later).

typedef unsigned short ushort_t;
typedef unsigned int uint_t;
typedef __attribute__((ext_vector_type(8))) short bf16x8;
typedef __attribute__((ext_vector_type(4))) float f32x4;

#define N_ROWS 32768
#define DIM 256
#define K_CODES 4096
#define NKS 2            // col strips (2048 cols each)
#define GATHER_BLOCKS 512
#define RG_BLOCKS (N_ROWS / 32)   // fused refine+gather: 32 rows/block

// ---- ws layout (mfma path), bytes ----
// Ehi      [0,       2097152)   bf16 [4096][256]   (dead after dist_mfma)
// Elo      [2097152, 4194304)                      (dead after dist_mfma)
// Et       [0,       4194304)   fp32 [4096][256]   (built after dist_mfma)
// cand     [4194304, 4718592)   int [32768][2 strips][2]
// esq      [6291456, 6307840)   float[4096]
// partials [6438912, 6443008)   float[1024]
#define WS_NEEDED (8u * 1024u * 1024u)

__device__ __forceinline__ unsigned short bf16_rne(float x) {
    unsigned u = __builtin_bit_cast(unsigned, x);
    unsigned r = u + 0x7fffu + ((u >> 16) & 1u);
    return (unsigned short)(r >> 16);
}
__device__ __forceinline__ float bf16_f(unsigned short h) {
    unsigned u = ((unsigned)h) << 16;
    return __builtin_bit_cast(float, u);
}
// total-order "better": smaller dist, tie -> smaller index
__device__ __forceinline__ bool better(float d, int c, float v, int i) {
    return (d < v) || (d == v && c < i);
}

// ---------------- prep: X -> Xh/Xl (bf16 split, row-major), into d_out -----
__global__ void prep_x(const float* __restrict__ X, ushort_t* __restrict__ Xh,
                       ushort_t* __restrict__ Xl) {
    int i = blockIdx.x * 256 + threadIdx.x;   // float4 index
    float4 v = ((const float4*)X)[i];
    ushort4 h, l;
    h.x = bf16_rne(v.x); l.x = bf16_rne(v.x - bf16_f(h.x));
    h.y = bf16_rne(v.y); l.y = bf16_rne(v.y - bf16_f(h.y));
    h.z = bf16_rne(v.z); l.z = bf16_rne(v.z - bf16_f(h.z));
    h.w = bf16_rne(v.w); l.w = bf16_rne(v.w - bf16_f(h.w));
    ((ushort4*)Xh)[i] = h;
    ((ushort4*)Xl)[i] = l;
}

// ------------- prep: E [256][4096] -> E^T hi/lo [4096][256] bf16 -----------
__global__ void prep_e(const float* __restrict__ E, ushort_t* __restrict__ Ehi,
                       ushort_t* __restrict__ Elo) {
    __shared__ ushort_t sh[64][66];
    __shared__ ushort_t sl[64][66];
    const int t = threadIdx.x;
    const int kbase = blockIdx.x * 64;
    const int dbase = blockIdx.y * 64;
#pragma unroll
    for (int i = 0; i < 16; ++i) {
        int lin = i * 256 + t;
        int dl = lin >> 6, kl = lin & 63;
        float v = E[(size_t)(dbase + dl) * K_CODES + kbase + kl];
        unsigned short h = bf16_rne(v);
        unsigned short l = bf16_rne(v - bf16_f(h));
        sh[kl][dl] = h;
        sl[kl][dl] = l;
    }
    __syncthreads();
#pragma unroll
    for (int i = 0; i < 8; ++i) {
        int lin = i * 256 + t;
        int kl = lin >> 5, d2 = (lin & 31) * 2;
        uint_t vh = (uint_t)sh[kl][d2] | ((uint_t)sh[kl][d2 + 1] << 16);
        uint_t vl = (uint_t)sl[kl][d2] | ((uint_t)sl[kl][d2 + 1] << 16);
        *(uint_t*)&Ehi[(size_t)(kbase + kl) * DIM + dbase + d2] = vh;
        *(uint_t*)&Elo[(size_t)(kbase + kl) * DIM + dbase + d2] = vl;
    }
}

// ------------- prep: E [256][4096] -> Et fp32 [4096][256] (exact) ----------
__global__ void prep_et(const float* __restrict__ E, float* __restrict__ Et) {
    __shared__ float s[64][65];
    const int t = threadIdx.x;
    const int kbase = blockIdx.x * 64;
    const int dbase = blockIdx.y * 64;
#pragma unroll
    for (int i = 0; i < 16; ++i) {
        int lin = i * 256 + t;
        int dl = lin >> 6, kl = lin & 63;
        s[kl][dl] = E[(size_t)(dbase + dl) * K_CODES + kbase + kl];
    }
    __syncthreads();
#pragma unroll
    for (int i = 0; i < 16; ++i) {
        int lin = i * 256 + t;
        int kl = lin >> 6, dl = lin & 63;
        Et[(size_t)(kbase + kl) * DIM + dbase + dl] = s[kl][dl];
    }
}

// ---------------- esq[k] = sum_d E[d][k]^2 (fp32, from original E) ---------
__global__ void esq_kernel(const float* __restrict__ E, float* __restrict__ esq) {
    __shared__ float red[16][17];
    int t = threadIdx.x;
    int kk = t & 15, dg = t >> 4;
    int k = blockIdx.x * 16 + kk;
    float a = 0.f;
#pragma unroll
    for (int it = 0; it < 16; ++it) {
        float e = E[(dg + it * 16) * K_CODES + k];
        a = fmaf(e, e, a);
    }
    red[dg][kk] = a;
    __syncthreads();
    if (t < 16) {
        float s = 0.f;
#pragma unroll
        for (int g = 0; g < 16; ++g) s += red[g][t];
        esq[blockIdx.x * 16 + t] = s;
    }
}

// ---------------- main: MFMA distance + per-strip top-2 (v15) --------------
// grid (NKS=2, 256) flattened+swizzled: 512 = 8 xcd x 64; xcd owns 32
// contiguous rowblocks x both strips; all 512 blocks co-resident (2/CU).
// 256 threads = 4 waves; wave w owns rows [w*32, w*32+32) (2 m-blocks) x
// all 128 cols of each ct tile. A (X hi/lo) fragments in registers (loaded
// once, 128 VGPRs; ~50 spill to L2-backed scratch under the 128-cap --
// amortized over 16 ct iterations); B (E^T hi/lo) staged to LDS
// double-buffered, 16 KB per kt step, stage issued before compute.
__global__ void __launch_bounds__(256, 2) dist_mfma(
    const ushort_t* __restrict__ Xh, const ushort_t* __restrict__ Xl,
    const ushort_t* __restrict__ Ehi, const ushort_t* __restrict__ Elo,
    const float* __restrict__ esq, int* __restrict__ cand) {
    __shared__ short lds[16384];   // 32 KB: buf p at p*8192 shorts,
                                   // within buf: Bh [0,4096) Bl [4096,8192)
    const int t = threadIdx.x;
    const int l = t & 63, w = t >> 6;
    const int l15 = l & 15, lg = l >> 4;

    // bijective XCD swizzle (512 blocks = 8 XCD x 64)
    const int wgid = blockIdx.x + blockIdx.y * NKS;
    const int xcd = wgid & 7, pos = wgid >> 3;
    const int ks = pos & 1;
    const int rowbase = (xcd * 32 + (pos >> 1)) * 128;

    const int n0 = 2 * w, n1 = 2 * w + 1;   // B n-blocks staged by this wave

#define GLDS(srcp, dstoff)                                                      \
    __builtin_amdgcn_global_load_lds(                                           \
        (const __attribute__((address_space(1))) void*)(srcp),                  \
        (__attribute__((address_space(3))) void*)&lds[dstoff], 16, 0, 0)
#define STAGE(pbuf, cbase, ktv) do {                                            \
    const uint_t o0 = (uint_t)((cbase) + n0 * 16 + l15) * DIM + (ktv) * 32 + lg * 8; \
    const uint_t o1 = (uint_t)((cbase) + n1 * 16 + l15) * DIM + (ktv) * 32 + lg * 8; \
    GLDS(Ehi + o0, (pbuf) * 8192 + n0 * 512);                                   \
    GLDS(Ehi + o1, (pbuf) * 8192 + n1 * 512);                                   \
    GLDS(Elo + o0, (pbuf) * 8192 + 4096 + n0 * 512);                            \
    GLDS(Elo + o1, (pbuf) * 8192 + 4096 + n1 * 512);                            \
} while (0)

    // issue first B-stage before the A prologue so DMA overlaps A latency
    STAGE(0, ks * 2048, 0);

    // ---- A prologue: 2 m-blocks x 8 kt, hi+lo fragments -> 128 VGPRs
    bf16x8 ah[2][8], al[2][8];
#pragma unroll
    for (int m = 0; m < 2; ++m) {
        const uint_t base = (uint_t)(rowbase + w * 32 + m * 16 + l15) * DIM + lg * 8;
#pragma unroll
        for (int kt = 0; kt < 8; ++kt) {
            ah[m][kt] = *(const bf16x8*)(Xh + base + kt * 32);
            al[m][kt] = *(const bf16x8*)(Xl + base + kt * 32);
        }
    }

    float v1[2][4], v2[2][4];
    int   i1[2][4], i2[2][4];
#pragma unroll
    for (int m = 0; m < 2; ++m)
#pragma unroll
        for (int q = 0; q < 4; ++q) {
            v1[m][q] = 3.4e38f; v2[m][q] = 3.4e38f;
            i1[m][q] = 0x7fffffff; i2[m][q] = 0x7fffffff;
        }

    __syncthreads();

#pragma unroll 1
    for (int ct = 0; ct < 16; ++ct) {
        const int cb = ks * 2048 + ct * 128;

        f32x4 acc[2][8];
#pragma unroll
        for (int m = 0; m < 2; ++m)
#pragma unroll
            for (int n = 0; n < 8; ++n) acc[m][n] = (f32x4){0.f, 0.f, 0.f, 0.f};

#pragma unroll
        for (int kt = 0; kt < 8; ++kt) {
            const int cur = kt & 1;
            // stage next (ct,kt) into the other buffer BEFORE compute
            if (kt < 7) {
                STAGE(cur ^ 1, cb, kt + 1);
            } else if (ct < 15) {
                STAGE(cur ^ 1, cb + 128, 0);
            }
            // compute current kt from buf[cur] (A from registers)
#pragma unroll
            for (int n = 0; n < 8; ++n) {
                const bf16x8 bh = *(const bf16x8*)&lds[cur * 8192 + n * 512 + l * 8];
                const bf16x8 bl = *(const bf16x8*)&lds[cur * 8192 + 4096 + n * 512 + l * 8];
#pragma unroll
                for (int m = 0; m < 2; ++m) {
                    acc[m][n] = __builtin_amdgcn_mfma_f32_16x16x32_bf16(
                        ah[m][kt], bh, acc[m][n], 0, 0, 0);
                    acc[m][n] = __builtin_amdgcn_mfma_f32_16x16x32_bf16(
                        ah[m][kt], bl, acc[m][n], 0, 0, 0);
                    acc[m][n] = __builtin_amdgcn_mfma_f32_16x16x32_bf16(
                        al[m][kt], bh, acc[m][n], 0, 0, 0);
                }
            }
            // barrier: drains vmcnt (next stage) + lgkm
            __syncthreads();
        }

        // epilogue: dist = esq - 2*dot, top-2 update per (m,q)
#pragma unroll
        for (int n = 0; n < 8; ++n) {
            const int col = cb + n * 16 + l15;
            const float eq = esq[col];
#pragma unroll
            for (int m = 0; m < 2; ++m)
#pragma unroll
                for (int q = 0; q < 4; ++q) {
                    const float d = fmaf(-2.f, acc[m][n][q], eq);
                    if (better(d, col, v1[m][q], i1[m][q])) {
                        v2[m][q] = v1[m][q]; i2[m][q] = i1[m][q];
                        v1[m][q] = d;        i1[m][q] = col;
                    } else if (better(d, col, v2[m][q], i2[m][q])) {
                        v2[m][q] = d; i2[m][q] = col;
                    }
                }
        }
    }
#undef STAGE
#undef GLDS

    // cross-lane top-2 merge over the 16 col-lanes (indices all distinct)
#pragma unroll
    for (int m = 0; m < 2; ++m)
#pragma unroll
        for (int q = 0; q < 4; ++q) {
            float a1 = v1[m][q], a2 = v2[m][q];
            int   b1 = i1[m][q], b2 = i2[m][q];
#pragma unroll
            for (int msk = 8; msk >= 1; msk >>= 1) {
                const float c1 = __shfl_xor(a1, msk, 64);
                const int   d1 = __shfl_xor(b1, msk, 64);
                const float c2 = __shfl_xor(a2, msk, 64);
                const int   d2 = __shfl_xor(b2, msk, 64);
                if (better(c1, d1, a1, b1)) {
                    if (better(a1, b1, c2, d2)) { a2 = a1; b2 = b1; }
                    else                        { a2 = c2; b2 = d2; }
                    a1 = c1; b1 = d1;
                } else {
                    if (better(c1, d1, a2, b2)) { a2 = c1; b2 = d1; }
                }
            }
            if (l15 == 0) {
                const int row = rowbase + w * 32 + m * 16 + lg * 4 + q;
                cand[(row * NKS + ks) * 2 + 0] = b1;
                cand[(row * NKS + ks) * 2 + 1] = b2;
            }
        }
}

// ------- fused refine (exact fp32 over 4 cands) + gather + loss ------------
// 4 waves/block, 8 rows each. Refine: lane = (cand 0..3) x (dim-group 0..15
// of 16 dims); xor-4/8/16/32 sum, then xor-2..1 argmin -> ALL lanes agree.
__global__ void refine_gather(const float* __restrict__ X, const float* __restrict__ Et,
                              const int* __restrict__ cand,
                              float* __restrict__ out, float* __restrict__ partials) {
    const int w = threadIdx.x >> 6, l = threadIdx.x & 63;
    const int cs = l & 3, dg = l >> 2;
    const int row0 = blockIdx.x * 32 + w * 8;
    float lsum = 0.f;

#pragma unroll 1
    for (int rr = 0; rr < 8; ++rr) {
        const int row = row0 + rr;
        const int c = cand[row * 4 + cs];
        const float4* ep = (const float4*)(Et + (size_t)c * DIM + dg * 16);
        const float4* xp = (const float4*)(X + (size_t)row * DIM + dg * 16);
        float p = 0.f;
#pragma unroll
        for (int j = 0; j < 4; ++j) {
            const float4 e = ep[j];
            const float4 x = xp[j];
            p = fmaf(e.x, fmaf(-2.f, x.x, e.x), p);
            p = fmaf(e.y, fmaf(-2.f, x.y, e.y), p);
            p = fmaf(e.z, fmaf(-2.f, x.z, e.z), p);
            p = fmaf(e.w, fmaf(-2.f, x.w, e.w), p);
        }
        p += __shfl_xor(p, 4, 64);
        p += __shfl_xor(p, 8, 64);
        p += __shfl_xor(p, 16, 64);
        p += __shfl_xor(p, 32, 64);
        float v = p; int id = c;
#pragma unroll
        for (int m = 2; m >= 1; m >>= 1) {
            const float v2 = __shfl_xor(v, m, 64);
            const int  id2 = __shfl_xor(id, m, 64);
            if (v2 < v || (v2 == v && id2 < id)) { v = v2; id = id2; }
        }
        // gather + loss (all lanes agree on id)
        const float4 x = *(const float4*)(X + (size_t)row * DIM + l * 4);
        const float4 q = *(const float4*)(Et + (size_t)id * DIM + l * 4);
        *(float4*)(out + (size_t)row * DIM + l * 4) = q;
        const float d0 = x.x - q.x, d1 = x.y - q.y, d2 = x.z - q.z, d3 = x.w - q.w;
        lsum += d0 * d0 + d1 * d1 + d2 * d2 + d3 * d3;
    }
#pragma unroll
    for (int m = 32; m >= 1; m >>= 1) lsum += __shfl_xor(lsum, m, 64);
    __shared__ float ws4[4];
    if (l == 0) ws4[w] = lsum;
    __syncthreads();
    if (threadIdx.x == 0) partials[blockIdx.x] = (ws4[0] + ws4[1]) + (ws4[2] + ws4[3]);
}

// -------- fallback fp32 dist (round-1 proven path, used if ws too small) ---
__global__ void dist_fp32(const float* __restrict__ X, const float* __restrict__ E,
                          const float* __restrict__ esq,
                          float* __restrict__ candv, int* __restrict__ candi) {
    __shared__ float Xs[8][128];
    __shared__ float Es[8][128];
    const int t = threadIdx.x;
    const int tx = t & 15;
    const int ty = t >> 4;
    const int rowbase = blockIdx.x * 128;
    const int ks = blockIdx.y;

    float minv[8];
    int   mini[8];
#pragma unroll
    for (int i = 0; i < 8; ++i) { minv[i] = 3.4e38f; mini[i] = 0; }

    for (int kt = 0; kt < 8; ++kt) {
        const int kbase = ks * 1024 + kt * 128;
        float acc[8][8];
#pragma unroll
        for (int i = 0; i < 8; ++i)
#pragma unroll
            for (int j = 0; j < 8; ++j) acc[i][j] = 0.f;

        for (int dc = 0; dc < DIM / 8; ++dc) {
            const int d0 = dc * 8;
            {
                const int row = t >> 1;
                const int dsl = (t & 1) * 4;
                const float4 xv = *(const float4*)(X + (size_t)(rowbase + row) * DIM + d0 + dsl);
                Xs[dsl + 0][row] = xv.x; Xs[dsl + 1][row] = xv.y;
                Xs[dsl + 2][row] = xv.z; Xs[dsl + 3][row] = xv.w;
            }
            {
                const int dr = t >> 5;
                const int c4 = (t & 31) * 4;
                const float4 ev = *(const float4*)(E + (size_t)(d0 + dr) * K_CODES + kbase + c4);
                *(float4*)&Es[dr][c4] = ev;
            }
            __syncthreads();
#pragma unroll
            for (int d = 0; d < 8; ++d) {
                float xr[8], er[8];
                *(float4*)&xr[0] = *(const float4*)&Xs[d][ty * 8];
                *(float4*)&xr[4] = *(const float4*)&Xs[d][ty * 8 + 4];
                *(float4*)&er[0] = *(const float4*)&Es[d][tx * 8];
                *(float4*)&er[4] = *(const float4*)&Es[d][tx * 8 + 4];
#pragma unroll
                for (int i = 0; i < 8; ++i)
#pragma unroll
                    for (int j = 0; j < 8; ++j)
                        acc[i][j] = fmaf(xr[i], er[j], acc[i][j]);
            }
            __syncthreads();
        }
        float eq[8];
        *(float4*)&eq[0] = *(const float4*)(esq + kbase + tx * 8);
        *(float4*)&eq[4] = *(const float4*)(esq + kbase + tx * 8 + 4);
#pragma unroll
        for (int i = 0; i < 8; ++i)
#pragma unroll
            for (int j = 0; j < 8; ++j) {
                const float dist = fmaf(-2.f, acc[i][j], eq[j]);
                if (dist < minv[i]) { minv[i] = dist; mini[i] = kbase + tx * 8 + j; }
            }
    }
#pragma unroll
    for (int i = 0; i < 8; ++i) {
        float v = minv[i];
        int   id = mini[i];
#pragma unroll
        for (int m = 8; m >= 1; m >>= 1) {
            const float v2 = __shfl_xor(v, m, 64);
            const int   i2 = __shfl_xor(id, m, 64);
            if (v2 < v || (v2 == v && i2 < id)) { v = v2; id = i2; }
        }
        if (tx == 0) {
            const int row = rowbase + ty * 8 + i;
            candv[row * 4 + ks] = v;
            candi[row * 4 + ks] = id;
        }
    }
}

__global__ void gather_loss(const float* __restrict__ X, const float* __restrict__ E,
                            const float* __restrict__ candv, const int* __restrict__ candi,
                            float* __restrict__ out, float* __restrict__ partials,
                            int nks) {
    const int w = threadIdx.x >> 6;
    const int l = threadIdx.x & 63;
    const int rowbase = blockIdx.x * (N_ROWS / GATHER_BLOCKS);
    float lsum = 0.f;

    for (int rr = w; rr < N_ROWS / GATHER_BLOCKS; rr += 4) {
        const int row = rowbase + rr;
        float bv = candv[row * nks];
        int   bi = candi[row * nks];
        for (int s = 1; s < nks; ++s) {
            const float v = candv[row * nks + s];
            const int  id = candi[row * nks + s];
            if (v < bv || (v == bv && id < bi)) { bv = v; bi = id; }
        }
        const float4 x = *(const float4*)(X + (size_t)row * DIM + l * 4);
        const float q0 = E[(size_t)(l * 4 + 0) * K_CODES + bi];
        const float q1 = E[(size_t)(l * 4 + 1) * K_CODES + bi];
        const float q2 = E[(size_t)(l * 4 + 2) * K_CODES + bi];
        const float q3 = E[(size_t)(l * 4 + 3) * K_CODES + bi];
        float4 q; q.x = q0; q.y = q1; q.z = q2; q.w = q3;
        *(float4*)(out + (size_t)row * DIM + l * 4) = q;
        const float d0 = x.x - q0, d1 = x.y - q1, d2 = x.z - q2, d3 = x.w - q3;
        lsum += d0 * d0 + d1 * d1 + d2 * d2 + d3 * d3;
    }
#pragma unroll
    for (int m = 32; m >= 1; m >>= 1) lsum += __shfl_xor(lsum, m, 64);
    __shared__ float ws4[4];
    if (l == 0) ws4[w] = lsum;
    __syncthreads();
    if (threadIdx.x == 0) partials[blockIdx.x] = (ws4[0] + ws4[1]) + (ws4[2] + ws4[3]);
}

__global__ void finalize(const float* __restrict__ partials, float* __restrict__ out_loss,
                         int npart) {
    __shared__ double s[256];
    double a = 0.0;
    for (int i = threadIdx.x; i < npart; i += 256) a += (double)partials[i];
    s[threadIdx.x] = a;
    __syncthreads();
    for (int st = 128; st > 0; st >>= 1) {
        if (threadIdx.x < st) s[threadIdx.x] += s[threadIdx.x + st];
        __syncthreads();
    }
    if (threadIdx.x == 0)
        out_loss[0] = (float)(1.25 * s[0] / (double)(N_ROWS * DIM));
}

extern "C" void kernel_launch(void* const* d_in, const int* in_sizes, int n_in,
                              void* d_out, int out_size, void* d_ws, size_t ws_size,
                              hipStream_t stream) {
    const float* X = (const float*)d_in[0];
    const float* E = (const float*)d_in[1];
    float* out = (float*)d_out;

    if (ws_size >= (size_t)WS_NEEDED) {
        // ---------------- MFMA path ----------------
        ushort_t* Ehi      = (ushort_t*)((char*)d_ws + 0);
        ushort_t* Elo      = (ushort_t*)((char*)d_ws + 2097152);
        float*    Et       = (float*)   ((char*)d_ws + 0);        // after dist_mfma
        int*      cand     = (int*)     ((char*)d_ws + 4194304);  // 512 KB
        float*    esq      = (float*)   ((char*)d_ws + 6291456);
        float*    partials = (float*)   ((char*)d_ws + 6438912);
        ushort_t* Xh       = (ushort_t*)d_out;                    // 16.78 MB
        ushort_t* Xl       = Xh + (size_t)N_ROWS * DIM;           // 16.78 MB

        prep_x<<<(N_ROWS * DIM / 4) / 256, 256, 0, stream>>>(X, Xh, Xl);
        prep_e<<<dim3(K_CODES / 64, DIM / 64), 256, 0, stream>>>(E, Ehi, Elo);
        esq_kernel<<<K_CODES / 16, 256, 0, stream>>>(E, esq);
        dist_mfma<<<dim3(NKS, N_ROWS / 128), 256, 0, stream>>>(
            Xh, Xl, Ehi, Elo, esq, cand);
        prep_et<<<dim3(K_CODES / 64, DIM / 64), 256, 0, stream>>>(E, Et);
        refine_gather<<<RG_BLOCKS, 256, 0, stream>>>(X, Et, cand, out, partials);
        finalize<<<1, 256, 0, stream>>>(partials, out + (size_t)N_ROWS * DIM, RG_BLOCKS);
    } else {
        // ---------------- fallback: round-1 fp32 path (needs ~1.07 MB) -----
        float* esq      = (float*)((char*)d_ws + 0);
        float* candv    = (float*)((char*)d_ws + 16384);
        int*   candi    = (int*)  ((char*)d_ws + 540672);
        float* partials = (float*)((char*)d_ws + 1064960);

        esq_kernel<<<K_CODES / 16, 256, 0, stream>>>(E, esq);
        dist_fp32<<<dim3(N_ROWS / 128, 4), 256, 0, stream>>>(X, E, esq, candv, candi);
        gather_loss<<<GATHER_BLOCKS, 256, 0, stream>>>(X, E, candv, candi, out,
                                                       partials, 4);
        finalize<<<1, 256, 0, stream>>>(partials, out + (size_t)N_ROWS * DIM,
                                        GATHER_BLOCKS);
    }
}

// Round 15
// 305.586 us; speedup vs baseline: 2.1978x; 1.0390x over previous
//
#include <hip/hip_runtime.h>

// Vector Quantizer, MFMA split-bf16 path + exact fp32 refine (row-major Et).
// inputs  d_in[0]: float32 X [32768, 256]
// emb     d_in[1]: float32 E [256, 4096]
// d_out: [8388608 floats e_k] + [1 float loss]
//
// dot(x,e) ~ 3 bf16 MFMAs: xh*eh + xh*el + xl*eh (fp32 accum).
// dist_mfma v16 = v15 (NKS=2, 512 co-resident blocks, A-register-file,
// B-only LDS dbuf) with an EXPLICIT register budget:
//   amdgpu_num_vgpr(256) + amdgpu_waves_per_eu(2,2) + flat_work_group_size
// pins the unified VGPR/AGPR budget at the 2-waves/SIMD point (512/256).
// Kernel needs ~250 unified (A-file 128 + acc 64 + top-2 32 + temps) -> no
// spill at the SAME residency where the 128-cap version spilled 133 MB.
// Top-2 per (row, 2048-col strip) -> 4 cands/row -> exact fp32 refine.
// Xh/Xl bf16 (row-major) staged in d_out (overwritten by gather later).

typedef unsigned short ushort_t;
typedef unsigned int uint_t;
typedef __attribute__((ext_vector_type(8))) short bf16x8;
typedef __attribute__((ext_vector_type(4))) float f32x4;

#define N_ROWS 32768
#define DIM 256
#define K_CODES 4096
#define NKS 2            // col strips (2048 cols each)
#define GATHER_BLOCKS 512
#define RG_BLOCKS (N_ROWS / 32)   // fused refine+gather: 32 rows/block

// ---- ws layout (mfma path), bytes ----
// Ehi      [0,       2097152)   bf16 [4096][256]   (dead after dist_mfma)
// Elo      [2097152, 4194304)                      (dead after dist_mfma)
// Et       [0,       4194304)   fp32 [4096][256]   (built after dist_mfma)
// cand     [4194304, 4718592)   int [32768][2 strips][2]
// esq      [6291456, 6307840)   float[4096]
// partials [6438912, 6443008)   float[1024]
#define WS_NEEDED (8u * 1024u * 1024u)

__device__ __forceinline__ unsigned short bf16_rne(float x) {
    unsigned u = __builtin_bit_cast(unsigned, x);
    unsigned r = u + 0x7fffu + ((u >> 16) & 1u);
    return (unsigned short)(r >> 16);
}
__device__ __forceinline__ float bf16_f(unsigned short h) {
    unsigned u = ((unsigned)h) << 16;
    return __builtin_bit_cast(float, u);
}
// total-order "better": smaller dist, tie -> smaller index
__device__ __forceinline__ bool better(float d, int c, float v, int i) {
    return (d < v) || (d == v && c < i);
}

// ---------------- prep: X -> Xh/Xl (bf16 split, row-major), into d_out -----
__global__ void prep_x(const float* __restrict__ X, ushort_t* __restrict__ Xh,
                       ushort_t* __restrict__ Xl) {
    int i = blockIdx.x * 256 + threadIdx.x;   // float4 index
    float4 v = ((const float4*)X)[i];
    ushort4 h, l;
    h.x = bf16_rne(v.x); l.x = bf16_rne(v.x - bf16_f(h.x));
    h.y = bf16_rne(v.y); l.y = bf16_rne(v.y - bf16_f(h.y));
    h.z = bf16_rne(v.z); l.z = bf16_rne(v.z - bf16_f(h.z));
    h.w = bf16_rne(v.w); l.w = bf16_rne(v.w - bf16_f(h.w));
    ((ushort4*)Xh)[i] = h;
    ((ushort4*)Xl)[i] = l;
}

// ------------- prep: E [256][4096] -> E^T hi/lo [4096][256] bf16 -----------
__global__ void prep_e(const float* __restrict__ E, ushort_t* __restrict__ Ehi,
                       ushort_t* __restrict__ Elo) {
    __shared__ ushort_t sh[64][66];
    __shared__ ushort_t sl[64][66];
    const int t = threadIdx.x;
    const int kbase = blockIdx.x * 64;
    const int dbase = blockIdx.y * 64;
#pragma unroll
    for (int i = 0; i < 16; ++i) {
        int lin = i * 256 + t;
        int dl = lin >> 6, kl = lin & 63;
        float v = E[(size_t)(dbase + dl) * K_CODES + kbase + kl];
        unsigned short h = bf16_rne(v);
        unsigned short l = bf16_rne(v - bf16_f(h));
        sh[kl][dl] = h;
        sl[kl][dl] = l;
    }
    __syncthreads();
#pragma unroll
    for (int i = 0; i < 8; ++i) {
        int lin = i * 256 + t;
        int kl = lin >> 5, d2 = (lin & 31) * 2;
        uint_t vh = (uint_t)sh[kl][d2] | ((uint_t)sh[kl][d2 + 1] << 16);
        uint_t vl = (uint_t)sl[kl][d2] | ((uint_t)sl[kl][d2 + 1] << 16);
        *(uint_t*)&Ehi[(size_t)(kbase + kl) * DIM + dbase + d2] = vh;
        *(uint_t*)&Elo[(size_t)(kbase + kl) * DIM + dbase + d2] = vl;
    }
}

// ------------- prep: E [256][4096] -> Et fp32 [4096][256] (exact) ----------
__global__ void prep_et(const float* __restrict__ E, float* __restrict__ Et) {
    __shared__ float s[64][65];
    const int t = threadIdx.x;
    const int kbase = blockIdx.x * 64;
    const int dbase = blockIdx.y * 64;
#pragma unroll
    for (int i = 0; i < 16; ++i) {
        int lin = i * 256 + t;
        int dl = lin >> 6, kl = lin & 63;
        s[kl][dl] = E[(size_t)(dbase + dl) * K_CODES + kbase + kl];
    }
    __syncthreads();
#pragma unroll
    for (int i = 0; i < 16; ++i) {
        int lin = i * 256 + t;
        int kl = lin >> 6, dl = lin & 63;
        Et[(size_t)(kbase + kl) * DIM + dbase + dl] = s[kl][dl];
    }
}

// ---------------- esq[k] = sum_d E[d][k]^2 (fp32, from original E) ---------
__global__ void esq_kernel(const float* __restrict__ E, float* __restrict__ esq) {
    __shared__ float red[16][17];
    int t = threadIdx.x;
    int kk = t & 15, dg = t >> 4;
    int k = blockIdx.x * 16 + kk;
    float a = 0.f;
#pragma unroll
    for (int it = 0; it < 16; ++it) {
        float e = E[(dg + it * 16) * K_CODES + k];
        a = fmaf(e, e, a);
    }
    red[dg][kk] = a;
    __syncthreads();
    if (t < 16) {
        float s = 0.f;
#pragma unroll
        for (int g = 0; g < 16; ++g) s += red[g][t];
        esq[blockIdx.x * 16 + t] = s;
    }
}

// ---------------- main: MFMA distance + per-strip top-2 (v16) --------------
// grid (NKS=2, 256) flattened+swizzled: 512 = 8 xcd x 64; xcd owns 32
// contiguous rowblocks x both strips; all 512 blocks co-resident (2/CU).
// 256 threads = 4 waves; wave w owns rows [w*32, w*32+32) (2 m-blocks) x
// all 128 cols of each ct tile. A (X hi/lo) fragments in registers (loaded
// once, 128 VGPRs); B (E^T hi/lo) staged to LDS double-buffered, 16 KB per
// kt step, stage issued before compute. Register budget pinned at 256
// unified (2 waves/SIMD) -> A-file + acc + top-2 fit WITHOUT spill.
__global__
__attribute__((amdgpu_flat_work_group_size(256, 256)))
__attribute__((amdgpu_waves_per_eu(2, 2)))
__attribute__((amdgpu_num_vgpr(256)))
void dist_mfma(
    const ushort_t* __restrict__ Xh, const ushort_t* __restrict__ Xl,
    const ushort_t* __restrict__ Ehi, const ushort_t* __restrict__ Elo,
    const float* __restrict__ esq, int* __restrict__ cand) {
    __shared__ short lds[16384];   // 32 KB: buf p at p*8192 shorts,
                                   // within buf: Bh [0,4096) Bl [4096,8192)
    const int t = threadIdx.x;
    const int l = t & 63, w = t >> 6;
    const int l15 = l & 15, lg = l >> 4;

    // bijective XCD swizzle (512 blocks = 8 XCD x 64)
    const int wgid = blockIdx.x + blockIdx.y * NKS;
    const int xcd = wgid & 7, pos = wgid >> 3;
    const int ks = pos & 1;
    const int rowbase = (xcd * 32 + (pos >> 1)) * 128;

    const int n0 = 2 * w, n1 = 2 * w + 1;   // B n-blocks staged by this wave

#define GLDS(srcp, dstoff)                                                      \
    __builtin_amdgcn_global_load_lds(                                           \
        (const __attribute__((address_space(1))) void*)(srcp),                  \
        (__attribute__((address_space(3))) void*)&lds[dstoff], 16, 0, 0)
#define STAGE(pbuf, cbase, ktv) do {                                            \
    const uint_t o0 = (uint_t)((cbase) + n0 * 16 + l15) * DIM + (ktv) * 32 + lg * 8; \
    const uint_t o1 = (uint_t)((cbase) + n1 * 16 + l15) * DIM + (ktv) * 32 + lg * 8; \
    GLDS(Ehi + o0, (pbuf) * 8192 + n0 * 512);                                   \
    GLDS(Ehi + o1, (pbuf) * 8192 + n1 * 512);                                   \
    GLDS(Elo + o0, (pbuf) * 8192 + 4096 + n0 * 512);                            \
    GLDS(Elo + o1, (pbuf) * 8192 + 4096 + n1 * 512);                            \
} while (0)

    // issue first B-stage before the A prologue so DMA overlaps A latency
    STAGE(0, ks * 2048, 0);

    // ---- A prologue: 2 m-blocks x 8 kt, hi+lo fragments -> 128 VGPRs
    bf16x8 ah[2][8], al[2][8];
#pragma unroll
    for (int m = 0; m < 2; ++m) {
        const uint_t base = (uint_t)(rowbase + w * 32 + m * 16 + l15) * DIM + lg * 8;
#pragma unroll
        for (int kt = 0; kt < 8; ++kt) {
            ah[m][kt] = *(const bf16x8*)(Xh + base + kt * 32);
            al[m][kt] = *(const bf16x8*)(Xl + base + kt * 32);
        }
    }

    float v1[2][4], v2[2][4];
    int   i1[2][4], i2[2][4];
#pragma unroll
    for (int m = 0; m < 2; ++m)
#pragma unroll
        for (int q = 0; q < 4; ++q) {
            v1[m][q] = 3.4e38f; v2[m][q] = 3.4e38f;
            i1[m][q] = 0x7fffffff; i2[m][q] = 0x7fffffff;
        }

    __syncthreads();

#pragma unroll 1
    for (int ct = 0; ct < 16; ++ct) {
        const int cb = ks * 2048 + ct * 128;

        f32x4 acc[2][8];
#pragma unroll
        for (int m = 0; m < 2; ++m)
#pragma unroll
            for (int n = 0; n < 8; ++n) acc[m][n] = (f32x4){0.f, 0.f, 0.f, 0.f};

#pragma unroll
        for (int kt = 0; kt < 8; ++kt) {
            const int cur = kt & 1;
            // stage next (ct,kt) into the other buffer BEFORE compute
            if (kt < 7) {
                STAGE(cur ^ 1, cb, kt + 1);
            } else if (ct < 15) {
                STAGE(cur ^ 1, cb + 128, 0);
            }
            // compute current kt from buf[cur] (A from registers)
#pragma unroll
            for (int n = 0; n < 8; ++n) {
                const bf16x8 bh = *(const bf16x8*)&lds[cur * 8192 + n * 512 + l * 8];
                const bf16x8 bl = *(const bf16x8*)&lds[cur * 8192 + 4096 + n * 512 + l * 8];
#pragma unroll
                for (int m = 0; m < 2; ++m) {
                    acc[m][n] = __builtin_amdgcn_mfma_f32_16x16x32_bf16(
                        ah[m][kt], bh, acc[m][n], 0, 0, 0);
                    acc[m][n] = __builtin_amdgcn_mfma_f32_16x16x32_bf16(
                        ah[m][kt], bl, acc[m][n], 0, 0, 0);
                    acc[m][n] = __builtin_amdgcn_mfma_f32_16x16x32_bf16(
                        al[m][kt], bh, acc[m][n], 0, 0, 0);
                }
            }
            // barrier: drains vmcnt (next stage) + lgkm
            __syncthreads();
        }

        // epilogue: dist = esq - 2*dot, top-2 update per (m,q)
#pragma unroll
        for (int n = 0; n < 8; ++n) {
            const int col = cb + n * 16 + l15;
            const float eq = esq[col];
#pragma unroll
            for (int m = 0; m < 2; ++m)
#pragma unroll
                for (int q = 0; q < 4; ++q) {
                    const float d = fmaf(-2.f, acc[m][n][q], eq);
                    if (better(d, col, v1[m][q], i1[m][q])) {
                        v2[m][q] = v1[m][q]; i2[m][q] = i1[m][q];
                        v1[m][q] = d;        i1[m][q] = col;
                    } else if (better(d, col, v2[m][q], i2[m][q])) {
                        v2[m][q] = d; i2[m][q] = col;
                    }
                }
        }
    }
#undef STAGE
#undef GLDS

    // cross-lane top-2 merge over the 16 col-lanes (indices all distinct)
#pragma unroll
    for (int m = 0; m < 2; ++m)
#pragma unroll
        for (int q = 0; q < 4; ++q) {
            float a1 = v1[m][q], a2 = v2[m][q];
            int   b1 = i1[m][q], b2 = i2[m][q];
#pragma unroll
            for (int msk = 8; msk >= 1; msk >>= 1) {
                const float c1 = __shfl_xor(a1, msk, 64);
                const int   d1 = __shfl_xor(b1, msk, 64);
                const float c2 = __shfl_xor(a2, msk, 64);
                const int   d2 = __shfl_xor(b2, msk, 64);
                if (better(c1, d1, a1, b1)) {
                    if (better(a1, b1, c2, d2)) { a2 = a1; b2 = b1; }
                    else                        { a2 = c2; b2 = d2; }
                    a1 = c1; b1 = d1;
                } else {
                    if (better(c1, d1, a2, b2)) { a2 = c1; b2 = d1; }
                }
            }
            if (l15 == 0) {
                const int row = rowbase + w * 32 + m * 16 + lg * 4 + q;
                cand[(row * NKS + ks) * 2 + 0] = b1;
                cand[(row * NKS + ks) * 2 + 1] = b2;
            }
        }
}

// ------- fused refine (exact fp32 over 4 cands) + gather + loss ------------
// 4 waves/block, 8 rows each. Refine: lane = (cand 0..3) x (dim-group 0..15
// of 16 dims); xor-4/8/16/32 sum, then xor-2..1 argmin -> ALL lanes agree.
__global__ void refine_gather(const float* __restrict__ X, const float* __restrict__ Et,
                              const int* __restrict__ cand,
                              float* __restrict__ out, float* __restrict__ partials) {
    const int w = threadIdx.x >> 6, l = threadIdx.x & 63;
    const int cs = l & 3, dg = l >> 2;
    const int row0 = blockIdx.x * 32 + w * 8;
    float lsum = 0.f;

#pragma unroll 1
    for (int rr = 0; rr < 8; ++rr) {
        const int row = row0 + rr;
        const int c = cand[row * 4 + cs];
        const float4* ep = (const float4*)(Et + (size_t)c * DIM + dg * 16);
        const float4* xp = (const float4*)(X + (size_t)row * DIM + dg * 16);
        float p = 0.f;
#pragma unroll
        for (int j = 0; j < 4; ++j) {
            const float4 e = ep[j];
            const float4 x = xp[j];
            p = fmaf(e.x, fmaf(-2.f, x.x, e.x), p);
            p = fmaf(e.y, fmaf(-2.f, x.y, e.y), p);
            p = fmaf(e.z, fmaf(-2.f, x.z, e.z), p);
            p = fmaf(e.w, fmaf(-2.f, x.w, e.w), p);
        }
        p += __shfl_xor(p, 4, 64);
        p += __shfl_xor(p, 8, 64);
        p += __shfl_xor(p, 16, 64);
        p += __shfl_xor(p, 32, 64);
        float v = p; int id = c;
#pragma unroll
        for (int m = 2; m >= 1; m >>= 1) {
            const float v2 = __shfl_xor(v, m, 64);
            const int  id2 = __shfl_xor(id, m, 64);
            if (v2 < v || (v2 == v && id2 < id)) { v = v2; id = id2; }
        }
        // gather + loss (all lanes agree on id)
        const float4 x = *(const float4*)(X + (size_t)row * DIM + l * 4);
        const float4 q = *(const float4*)(Et + (size_t)id * DIM + l * 4);
        *(float4*)(out + (size_t)row * DIM + l * 4) = q;
        const float d0 = x.x - q.x, d1 = x.y - q.y, d2 = x.z - q.z, d3 = x.w - q.w;
        lsum += d0 * d0 + d1 * d1 + d2 * d2 + d3 * d3;
    }
#pragma unroll
    for (int m = 32; m >= 1; m >>= 1) lsum += __shfl_xor(lsum, m, 64);
    __shared__ float ws4[4];
    if (l == 0) ws4[w] = lsum;
    __syncthreads();
    if (threadIdx.x == 0) partials[blockIdx.x] = (ws4[0] + ws4[1]) + (ws4[2] + ws4[3]);
}

// -------- fallback fp32 dist (round-1 proven path, used if ws too small) ---
__global__ void dist_fp32(const float* __restrict__ X, const float* __restrict__ E,
                          const float* __restrict__ esq,
                          float* __restrict__ candv, int* __restrict__ candi) {
    __shared__ float Xs[8][128];
    __shared__ float Es[8][128];
    const int t = threadIdx.x;
    const int tx = t & 15;
    const int ty = t >> 4;
    const int rowbase = blockIdx.x * 128;
    const int ks = blockIdx.y;

    float minv[8];
    int   mini[8];
#pragma unroll
    for (int i = 0; i < 8; ++i) { minv[i] = 3.4e38f; mini[i] = 0; }

    for (int kt = 0; kt < 8; ++kt) {
        const int kbase = ks * 1024 + kt * 128;
        float acc[8][8];
#pragma unroll
        for (int i = 0; i < 8; ++i)
#pragma unroll
            for (int j = 0; j < 8; ++j) acc[i][j] = 0.f;

        for (int dc = 0; dc < DIM / 8; ++dc) {
            const int d0 = dc * 8;
            {
                const int row = t >> 1;
                const int dsl = (t & 1) * 4;
                const float4 xv = *(const float4*)(X + (size_t)(rowbase + row) * DIM + d0 + dsl);
                Xs[dsl + 0][row] = xv.x; Xs[dsl + 1][row] = xv.y;
                Xs[dsl + 2][row] = xv.z; Xs[dsl + 3][row] = xv.w;
            }
            {
                const int dr = t >> 5;
                const int c4 = (t & 31) * 4;
                const float4 ev = *(const float4*)(E + (size_t)(d0 + dr) * K_CODES + kbase + c4);
                *(float4*)&Es[dr][c4] = ev;
            }
            __syncthreads();
#pragma unroll
            for (int d = 0; d < 8; ++d) {
                float xr[8], er[8];
                *(float4*)&xr[0] = *(const float4*)&Xs[d][ty * 8];
                *(float4*)&xr[4] = *(const float4*)&Xs[d][ty * 8 + 4];
                *(float4*)&er[0] = *(const float4*)&Es[d][tx * 8];
                *(float4*)&er[4] = *(const float4*)&Es[d][tx * 8 + 4];
#pragma unroll
                for (int i = 0; i < 8; ++i)
#pragma unroll
                    for (int j = 0; j < 8; ++j)
                        acc[i][j] = fmaf(xr[i], er[j], acc[i][j]);
            }
            __syncthreads();
        }
        float eq[8];
        *(float4*)&eq[0] = *(const float4*)(esq + kbase + tx * 8);
        *(float4*)&eq[4] = *(const float4*)(esq + kbase + tx * 8 + 4);
#pragma unroll
        for (int i = 0; i < 8; ++i)
#pragma unroll
            for (int j = 0; j < 8; ++j) {
                const float dist = fmaf(-2.f, acc[i][j], eq[j]);
                if (dist < minv[i]) { minv[i] = dist; mini[i] = kbase + tx * 8 + j; }
            }
    }
#pragma unroll
    for (int i = 0; i < 8; ++i) {
        float v = minv[i];
        int   id = mini[i];
#pragma unroll
        for (int m = 8; m >= 1; m >>= 1) {
            const float v2 = __shfl_xor(v, m, 64);
            const int   i2 = __shfl_xor(id, m, 64);
            if (v2 < v || (v2 == v && i2 < id)) { v = v2; id = i2; }
        }
        if (tx == 0) {
            const int row = rowbase + ty * 8 + i;
            candv[row * 4 + ks] = v;
            candi[row * 4 + ks] = id;
        }
    }
}

__global__ void gather_loss(const float* __restrict__ X, const float* __restrict__ E,
                            const float* __restrict__ candv, const int* __restrict__ candi,
                            float* __restrict__ out, float* __restrict__ partials,
                            int nks) {
    const int w = threadIdx.x >> 6;
    const int l = threadIdx.x & 63;
    const int rowbase = blockIdx.x * (N_ROWS / GATHER_BLOCKS);
    float lsum = 0.f;

    for (int rr = w; rr < N_ROWS / GATHER_BLOCKS; rr += 4) {
        const int row = rowbase + rr;
        float bv = candv[row * nks];
        int   bi = candi[row * nks];
        for (int s = 1; s < nks; ++s) {
            const float v = candv[row * nks + s];
            const int  id = candi[row * nks + s];
            if (v < bv || (v == bv && id < bi)) { bv = v; bi = id; }
        }
        const float4 x = *(const float4*)(X + (size_t)row * DIM + l * 4);
        const float q0 = E[(size_t)(l * 4 + 0) * K_CODES + bi];
        const float q1 = E[(size_t)(l * 4 + 1) * K_CODES + bi];
        const float q2 = E[(size_t)(l * 4 + 2) * K_CODES + bi];
        const float q3 = E[(size_t)(l * 4 + 3) * K_CODES + bi];
        float4 q; q.x = q0; q.y = q1; q.z = q2; q.w = q3;
        *(float4*)(out + (size_t)row * DIM + l * 4) = q;
        const float d0 = x.x - q0, d1 = x.y - q1, d2 = x.z - q2, d3 = x.w - q3;
        lsum += d0 * d0 + d1 * d1 + d2 * d2 + d3 * d3;
    }
#pragma unroll
    for (int m = 32; m >= 1; m >>= 1) lsum += __shfl_xor(lsum, m, 64);
    __shared__ float ws4[4];
    if (l == 0) ws4[w] = lsum;
    __syncthreads();
    if (threadIdx.x == 0) partials[blockIdx.x] = (ws4[0] + ws4[1]) + (ws4[2] + ws4[3]);
}

__global__ void finalize(const float* __restrict__ partials, float* __restrict__ out_loss,
                         int npart) {
    __shared__ double s[256];
    double a = 0.0;
    for (int i = threadIdx.x; i < npart; i += 256) a += (double)partials[i];
    s[threadIdx.x] = a;
    __syncthreads();
    for (int st = 128; st > 0; st >>= 1) {
        if (threadIdx.x < st) s[threadIdx.x] += s[threadIdx.x + st];
        __syncthreads();
    }
    if (threadIdx.x == 0)
        out_loss[0] = (float)(1.25 * s[0] / (double)(N_ROWS * DIM));
}

extern "C" void kernel_launch(void* const* d_in, const int* in_sizes, int n_in,
                              void* d_out, int out_size, void* d_ws, size_t ws_size,
                              hipStream_t stream) {
    const float* X = (const float*)d_in[0];
    const float* E = (const float*)d_in[1];
    float* out = (float*)d_out;

    if (ws_size >= (size_t)WS_NEEDED) {
        // ---------------- MFMA path ----------------
        ushort_t* Ehi      = (ushort_t*)((char*)d_ws + 0);
        ushort_t* Elo      = (ushort_t*)((char*)d_ws + 2097152);
        float*    Et       = (float*)   ((char*)d_ws + 0);        // after dist_mfma
        int*      cand     = (int*)     ((char*)d_ws + 4194304);  // 512 KB
        float*    esq      = (float*)   ((char*)d_ws + 6291456);
        float*    partials = (float*)   ((char*)d_ws + 6438912);
        ushort_t* Xh       = (ushort_t*)d_out;                    // 16.78 MB
        ushort_t* Xl       = Xh + (size_t)N_ROWS * DIM;           // 16.78 MB

        prep_x<<<(N_ROWS * DIM / 4) / 256, 256, 0, stream>>>(X, Xh, Xl);
        prep_e<<<dim3(K_CODES / 64, DIM / 64), 256, 0, stream>>>(E, Ehi, Elo);
        esq_kernel<<<K_CODES / 16, 256, 0, stream>>>(E, esq);
        dist_mfma<<<dim3(NKS, N_ROWS / 128), 256, 0, stream>>>(
            Xh, Xl, Ehi, Elo, esq, cand);
        prep_et<<<dim3(K_CODES / 64, DIM / 64), 256, 0, stream>>>(E, Et);
        refine_gather<<<RG_BLOCKS, 256, 0, stream>>>(X, Et, cand, out, partials);
        finalize<<<1, 256, 0, stream>>>(partials, out + (size_t)N_ROWS * DIM, RG_BLOCKS);
    } else {
        // ---------------- fallback: round-1 fp32 path (needs ~1.07 MB) -----
        float* esq      = (float*)((char*)d_ws + 0);
        float* candv    = (float*)((char*)d_ws + 16384);
        int*   candi    = (int*)  ((char*)d_ws + 540672);
        float* partials = (float*)((char*)d_ws + 1064960);

        esq_kernel<<<K_CODES / 16, 256, 0, stream>>>(E, esq);
        dist_fp32<<<dim3(N_ROWS / 128, 4), 256, 0, stream>>>(X, E, esq, candv, candi);
        gather_loss<<<GATHER_BLOCKS, 256, 0, stream>>>(X, E, candv, candi, out,
                                                       partials, 4);
        finalize<<<1, 256, 0, stream>>>(partials, out + (size_t)N_ROWS * DIM,
                                        GATHER_BLOCKS);
    }
}

// Round 16
// 300.526 us; speedup vs baseline: 2.2348x; 1.0168x over previous
//
#include <hip/hip_runtime.h>

// Vector Quantizer, MFMA split-bf16 path + exact fp32 refine (row-major Et).
// inputs  d_in[0]: float32 X [32768, 256]
// emb     d_in[1]: float32 E [256, 4096]
// d_out: [8388608 floats e_k] + [1 float loss]
//
// dot(x,e) ~ 3 bf16 MFMAs: xh*eh + xh*el + xl*eh (fp32 accum).
// dist_mfma v17 = v16 (NKS=2, A-register-file, B-only LDS dbuf, pinned
// 2-waves/EU budget) with the TOP-2 STATE MOVED TO LDS (32 KB, [slot][tid]
// layout -> conflict-free). Unified register need drops to ~216 <= 256:
// A-file 128 + acc 64 (AGPR) + temps -- genuinely zero spill (v16 still
// spilled 67 MB because A-file+acc+top2+temps ~250 was marginal).
// Top-2 per (row, 2048-col strip) -> 4 cands/row -> exact fp32 refine.
// Xh/Xl bf16 (row-major) staged in d_out (overwritten by gather later).

typedef unsigned short ushort_t;
typedef unsigned int uint_t;
typedef __attribute__((ext_vector_type(8))) short bf16x8;
typedef __attribute__((ext_vector_type(4))) float f32x4;

#define N_ROWS 32768
#define DIM 256
#define K_CODES 4096
#define NKS 2            // col strips (2048 cols each)
#define GATHER_BLOCKS 512
#define RG_BLOCKS (N_ROWS / 32)   // fused refine+gather: 32 rows/block

// ---- ws layout (mfma path), bytes ----
// Ehi      [0,       2097152)   bf16 [4096][256]   (dead after dist_mfma)
// Elo      [2097152, 4194304)                      (dead after dist_mfma)
// Et       [0,       4194304)   fp32 [4096][256]   (built after dist_mfma)
// cand     [4194304, 4718592)   int [32768][2 strips][2]
// esq      [6291456, 6307840)   float[4096]
// partials [6438912, 6443008)   float[1024]
#define WS_NEEDED (8u * 1024u * 1024u)

__device__ __forceinline__ unsigned short bf16_rne(float x) {
    unsigned u = __builtin_bit_cast(unsigned, x);
    unsigned r = u + 0x7fffu + ((u >> 16) & 1u);
    return (unsigned short)(r >> 16);
}
__device__ __forceinline__ float bf16_f(unsigned short h) {
    unsigned u = ((unsigned)h) << 16;
    return __builtin_bit_cast(float, u);
}
// total-order "better": smaller dist, tie -> smaller index
__device__ __forceinline__ bool better(float d, int c, float v, int i) {
    return (d < v) || (d == v && c < i);
}

// ---------------- prep: X -> Xh/Xl (bf16 split, row-major), into d_out -----
__global__ void prep_x(const float* __restrict__ X, ushort_t* __restrict__ Xh,
                       ushort_t* __restrict__ Xl) {
    int i = blockIdx.x * 256 + threadIdx.x;   // float4 index
    float4 v = ((const float4*)X)[i];
    ushort4 h, l;
    h.x = bf16_rne(v.x); l.x = bf16_rne(v.x - bf16_f(h.x));
    h.y = bf16_rne(v.y); l.y = bf16_rne(v.y - bf16_f(h.y));
    h.z = bf16_rne(v.z); l.z = bf16_rne(v.z - bf16_f(h.z));
    h.w = bf16_rne(v.w); l.w = bf16_rne(v.w - bf16_f(h.w));
    ((ushort4*)Xh)[i] = h;
    ((ushort4*)Xl)[i] = l;
}

// ------------- prep: E [256][4096] -> E^T hi/lo [4096][256] bf16 -----------
__global__ void prep_e(const float* __restrict__ E, ushort_t* __restrict__ Ehi,
                       ushort_t* __restrict__ Elo) {
    __shared__ ushort_t sh[64][66];
    __shared__ ushort_t sl[64][66];
    const int t = threadIdx.x;
    const int kbase = blockIdx.x * 64;
    const int dbase = blockIdx.y * 64;
#pragma unroll
    for (int i = 0; i < 16; ++i) {
        int lin = i * 256 + t;
        int dl = lin >> 6, kl = lin & 63;
        float v = E[(size_t)(dbase + dl) * K_CODES + kbase + kl];
        unsigned short h = bf16_rne(v);
        unsigned short l = bf16_rne(v - bf16_f(h));
        sh[kl][dl] = h;
        sl[kl][dl] = l;
    }
    __syncthreads();
#pragma unroll
    for (int i = 0; i < 8; ++i) {
        int lin = i * 256 + t;
        int kl = lin >> 5, d2 = (lin & 31) * 2;
        uint_t vh = (uint_t)sh[kl][d2] | ((uint_t)sh[kl][d2 + 1] << 16);
        uint_t vl = (uint_t)sl[kl][d2] | ((uint_t)sl[kl][d2 + 1] << 16);
        *(uint_t*)&Ehi[(size_t)(kbase + kl) * DIM + dbase + d2] = vh;
        *(uint_t*)&Elo[(size_t)(kbase + kl) * DIM + dbase + d2] = vl;
    }
}

// ------------- prep: E [256][4096] -> Et fp32 [4096][256] (exact) ----------
__global__ void prep_et(const float* __restrict__ E, float* __restrict__ Et) {
    __shared__ float s[64][65];
    const int t = threadIdx.x;
    const int kbase = blockIdx.x * 64;
    const int dbase = blockIdx.y * 64;
#pragma unroll
    for (int i = 0; i < 16; ++i) {
        int lin = i * 256 + t;
        int dl = lin >> 6, kl = lin & 63;
        s[kl][dl] = E[(size_t)(dbase + dl) * K_CODES + kbase + kl];
    }
    __syncthreads();
#pragma unroll
    for (int i = 0; i < 16; ++i) {
        int lin = i * 256 + t;
        int kl = lin >> 6, dl = lin & 63;
        Et[(size_t)(kbase + kl) * DIM + dbase + dl] = s[kl][dl];
    }
}

// ---------------- esq[k] = sum_d E[d][k]^2 (fp32, from original E) ---------
__global__ void esq_kernel(const float* __restrict__ E, float* __restrict__ esq) {
    __shared__ float red[16][17];
    int t = threadIdx.x;
    int kk = t & 15, dg = t >> 4;
    int k = blockIdx.x * 16 + kk;
    float a = 0.f;
#pragma unroll
    for (int it = 0; it < 16; ++it) {
        float e = E[(dg + it * 16) * K_CODES + k];
        a = fmaf(e, e, a);
    }
    red[dg][kk] = a;
    __syncthreads();
    if (t < 16) {
        float s = 0.f;
#pragma unroll
        for (int g = 0; g < 16; ++g) s += red[g][t];
        esq[blockIdx.x * 16 + t] = s;
    }
}

// ---------------- main: MFMA distance + per-strip top-2 (v17) --------------
// grid (NKS=2, 256) flattened+swizzled: 512 = 8 xcd x 64; xcd owns 32
// contiguous rowblocks x both strips; all 512 blocks co-resident (2/CU).
// 256 threads = 4 waves; wave w owns rows [w*32, w*32+32) (2 m-blocks) x
// all 128 cols of each ct tile. A (X hi/lo) fragments in registers; B (E^T
// hi/lo) staged to LDS double-buffered, 16 KB per kt step, stage issued
// before compute. TOP-2 STATE IN LDS (s_state[32][256], [slot][tid] ->
// conflict-free, thread-private, touched once per ct). Unified registers:
// A 128 + acc 64 (AGPR) + temps ~24 = ~216 <= 256 @ 2 waves/EU -> no spill.
__global__
__attribute__((amdgpu_flat_work_group_size(256, 256)))
__attribute__((amdgpu_waves_per_eu(2, 2)))
__attribute__((amdgpu_num_vgpr(256)))
void dist_mfma(
    const ushort_t* __restrict__ Xh, const ushort_t* __restrict__ Xl,
    const ushort_t* __restrict__ Ehi, const ushort_t* __restrict__ Elo,
    const float* __restrict__ esq, int* __restrict__ cand) {
    __shared__ short lds[16384];        // 32 KB B staging (2 x 16 KB bufs)
    __shared__ uint_t s_state[32][256]; // 32 KB top-2 state:
                                        // [0..7]=v1 [8..15]=v2 [16..23]=i1 [24..31]=i2
    const int t = threadIdx.x;
    const int l = t & 63, w = t >> 6;
    const int l15 = l & 15, lg = l >> 4;

    // bijective XCD swizzle (512 blocks = 8 XCD x 64)
    const int wgid = blockIdx.x + blockIdx.y * NKS;
    const int xcd = wgid & 7, pos = wgid >> 3;
    const int ks = pos & 1;
    const int rowbase = (xcd * 32 + (pos >> 1)) * 128;

    const int n0 = 2 * w, n1 = 2 * w + 1;   // B n-blocks staged by this wave

#define GLDS(srcp, dstoff)                                                      \
    __builtin_amdgcn_global_load_lds(                                           \
        (const __attribute__((address_space(1))) void*)(srcp),                  \
        (__attribute__((address_space(3))) void*)&lds[dstoff], 16, 0, 0)
#define STAGE(pbuf, cbase, ktv) do {                                            \
    const uint_t o0 = (uint_t)((cbase) + n0 * 16 + l15) * DIM + (ktv) * 32 + lg * 8; \
    const uint_t o1 = (uint_t)((cbase) + n1 * 16 + l15) * DIM + (ktv) * 32 + lg * 8; \
    GLDS(Ehi + o0, (pbuf) * 8192 + n0 * 512);                                   \
    GLDS(Ehi + o1, (pbuf) * 8192 + n1 * 512);                                   \
    GLDS(Elo + o0, (pbuf) * 8192 + 4096 + n0 * 512);                            \
    GLDS(Elo + o1, (pbuf) * 8192 + 4096 + n1 * 512);                            \
} while (0)

    // issue first B-stage before the A prologue so DMA overlaps A latency
    STAGE(0, ks * 2048, 0);

    // ---- A prologue: 2 m-blocks x 8 kt, hi+lo fragments -> 128 VGPRs
    bf16x8 ah[2][8], al[2][8];
#pragma unroll
    for (int m = 0; m < 2; ++m) {
        const uint_t base = (uint_t)(rowbase + w * 32 + m * 16 + l15) * DIM + lg * 8;
#pragma unroll
        for (int kt = 0; kt < 8; ++kt) {
            ah[m][kt] = *(const bf16x8*)(Xh + base + kt * 32);
            al[m][kt] = *(const bf16x8*)(Xl + base + kt * 32);
        }
    }

    // init top-2 state in LDS (thread-private slots, no barrier needed)
#pragma unroll
    for (int s = 0; s < 8; ++s) {
        s_state[s][t]      = __builtin_bit_cast(uint_t, 3.4e38f);
        s_state[8 + s][t]  = __builtin_bit_cast(uint_t, 3.4e38f);
        s_state[16 + s][t] = 0x7fffffffu;
        s_state[24 + s][t] = 0x7fffffffu;
    }

    __syncthreads();

#pragma unroll 1
    for (int ct = 0; ct < 16; ++ct) {
        const int cb = ks * 2048 + ct * 128;

        f32x4 acc[2][8];
#pragma unroll
        for (int m = 0; m < 2; ++m)
#pragma unroll
            for (int n = 0; n < 8; ++n) acc[m][n] = (f32x4){0.f, 0.f, 0.f, 0.f};

#pragma unroll
        for (int kt = 0; kt < 8; ++kt) {
            const int cur = kt & 1;
            // stage next (ct,kt) into the other buffer BEFORE compute
            if (kt < 7) {
                STAGE(cur ^ 1, cb, kt + 1);
            } else if (ct < 15) {
                STAGE(cur ^ 1, cb + 128, 0);
            }
            // compute current kt from buf[cur] (A from registers)
#pragma unroll
            for (int n = 0; n < 8; ++n) {
                const bf16x8 bh = *(const bf16x8*)&lds[cur * 8192 + n * 512 + l * 8];
                const bf16x8 bl = *(const bf16x8*)&lds[cur * 8192 + 4096 + n * 512 + l * 8];
#pragma unroll
                for (int m = 0; m < 2; ++m) {
                    acc[m][n] = __builtin_amdgcn_mfma_f32_16x16x32_bf16(
                        ah[m][kt], bh, acc[m][n], 0, 0, 0);
                    acc[m][n] = __builtin_amdgcn_mfma_f32_16x16x32_bf16(
                        ah[m][kt], bl, acc[m][n], 0, 0, 0);
                    acc[m][n] = __builtin_amdgcn_mfma_f32_16x16x32_bf16(
                        al[m][kt], bh, acc[m][n], 0, 0, 0);
                }
            }
            // barrier: drains vmcnt (next stage) + lgkm
            __syncthreads();
        }

        // epilogue: dist = esq - 2*dot, top-2 update per (m,q); state in LDS
        float eq[8];
#pragma unroll
        for (int n = 0; n < 8; ++n) eq[n] = esq[cb + n * 16 + l15];
#pragma unroll
        for (int m = 0; m < 2; ++m)
#pragma unroll
            for (int q = 0; q < 4; ++q) {
                const int s = m * 4 + q;
                float v1 = __builtin_bit_cast(float, s_state[s][t]);
                float v2 = __builtin_bit_cast(float, s_state[8 + s][t]);
                int   i1 = (int)s_state[16 + s][t];
                int   i2 = (int)s_state[24 + s][t];
#pragma unroll
                for (int n = 0; n < 8; ++n) {
                    const int col = cb + n * 16 + l15;
                    const float d = fmaf(-2.f, acc[m][n][q], eq[n]);
                    if (better(d, col, v1, i1)) {
                        v2 = v1; i2 = i1;
                        v1 = d;  i1 = col;
                    } else if (better(d, col, v2, i2)) {
                        v2 = d; i2 = col;
                    }
                }
                s_state[s][t]      = __builtin_bit_cast(uint_t, v1);
                s_state[8 + s][t]  = __builtin_bit_cast(uint_t, v2);
                s_state[16 + s][t] = (uint_t)i1;
                s_state[24 + s][t] = (uint_t)i2;
            }
    }
#undef STAGE
#undef GLDS

    // cross-lane top-2 merge over the 16 col-lanes (indices all distinct)
#pragma unroll
    for (int m = 0; m < 2; ++m)
#pragma unroll
        for (int q = 0; q < 4; ++q) {
            const int s = m * 4 + q;
            float a1 = __builtin_bit_cast(float, s_state[s][t]);
            float a2 = __builtin_bit_cast(float, s_state[8 + s][t]);
            int   b1 = (int)s_state[16 + s][t];
            int   b2 = (int)s_state[24 + s][t];
#pragma unroll
            for (int msk = 8; msk >= 1; msk >>= 1) {
                const float c1 = __shfl_xor(a1, msk, 64);
                const int   d1 = __shfl_xor(b1, msk, 64);
                const float c2 = __shfl_xor(a2, msk, 64);
                const int   d2 = __shfl_xor(b2, msk, 64);
                if (better(c1, d1, a1, b1)) {
                    if (better(a1, b1, c2, d2)) { a2 = a1; b2 = b1; }
                    else                        { a2 = c2; b2 = d2; }
                    a1 = c1; b1 = d1;
                } else {
                    if (better(c1, d1, a2, b2)) { a2 = c1; b2 = d1; }
                }
            }
            if (l15 == 0) {
                const int row = rowbase + w * 32 + m * 16 + lg * 4 + q;
                cand[(row * NKS + ks) * 2 + 0] = b1;
                cand[(row * NKS + ks) * 2 + 1] = b2;
            }
        }
}

// ------- fused refine (exact fp32 over 4 cands) + gather + loss ------------
// 4 waves/block, 8 rows each. Refine: lane = (cand 0..3) x (dim-group 0..15
// of 16 dims); xor-4/8/16/32 sum, then xor-2..1 argmin -> ALL lanes agree.
__global__ void refine_gather(const float* __restrict__ X, const float* __restrict__ Et,
                              const int* __restrict__ cand,
                              float* __restrict__ out, float* __restrict__ partials) {
    const int w = threadIdx.x >> 6, l = threadIdx.x & 63;
    const int cs = l & 3, dg = l >> 2;
    const int row0 = blockIdx.x * 32 + w * 8;
    float lsum = 0.f;

#pragma unroll 1
    for (int rr = 0; rr < 8; ++rr) {
        const int row = row0 + rr;
        const int c = cand[row * 4 + cs];
        const float4* ep = (const float4*)(Et + (size_t)c * DIM + dg * 16);
        const float4* xp = (const float4*)(X + (size_t)row * DIM + dg * 16);
        float p = 0.f;
#pragma unroll
        for (int j = 0; j < 4; ++j) {
            const float4 e = ep[j];
            const float4 x = xp[j];
            p = fmaf(e.x, fmaf(-2.f, x.x, e.x), p);
            p = fmaf(e.y, fmaf(-2.f, x.y, e.y), p);
            p = fmaf(e.z, fmaf(-2.f, x.z, e.z), p);
            p = fmaf(e.w, fmaf(-2.f, x.w, e.w), p);
        }
        p += __shfl_xor(p, 4, 64);
        p += __shfl_xor(p, 8, 64);
        p += __shfl_xor(p, 16, 64);
        p += __shfl_xor(p, 32, 64);
        float v = p; int id = c;
#pragma unroll
        for (int m = 2; m >= 1; m >>= 1) {
            const float v2 = __shfl_xor(v, m, 64);
            const int  id2 = __shfl_xor(id, m, 64);
            if (v2 < v || (v2 == v && id2 < id)) { v = v2; id = id2; }
        }
        // gather + loss (all lanes agree on id)
        const float4 x = *(const float4*)(X + (size_t)row * DIM + l * 4);
        const float4 q = *(const float4*)(Et + (size_t)id * DIM + l * 4);
        *(float4*)(out + (size_t)row * DIM + l * 4) = q;
        const float d0 = x.x - q.x, d1 = x.y - q.y, d2 = x.z - q.z, d3 = x.w - q.w;
        lsum += d0 * d0 + d1 * d1 + d2 * d2 + d3 * d3;
    }
#pragma unroll
    for (int m = 32; m >= 1; m >>= 1) lsum += __shfl_xor(lsum, m, 64);
    __shared__ float ws4[4];
    if (l == 0) ws4[w] = lsum;
    __syncthreads();
    if (threadIdx.x == 0) partials[blockIdx.x] = (ws4[0] + ws4[1]) + (ws4[2] + ws4[3]);
}

// -------- fallback fp32 dist (round-1 proven path, used if ws too small) ---
__global__ void dist_fp32(const float* __restrict__ X, const float* __restrict__ E,
                          const float* __restrict__ esq,
                          float* __restrict__ candv, int* __restrict__ candi) {
    __shared__ float Xs[8][128];
    __shared__ float Es[8][128];
    const int t = threadIdx.x;
    const int tx = t & 15;
    const int ty = t >> 4;
    const int rowbase = blockIdx.x * 128;
    const int ks = blockIdx.y;

    float minv[8];
    int   mini[8];
#pragma unroll
    for (int i = 0; i < 8; ++i) { minv[i] = 3.4e38f; mini[i] = 0; }

    for (int kt = 0; kt < 8; ++kt) {
        const int kbase = ks * 1024 + kt * 128;
        float acc[8][8];
#pragma unroll
        for (int i = 0; i < 8; ++i)
#pragma unroll
            for (int j = 0; j < 8; ++j) acc[i][j] = 0.f;

        for (int dc = 0; dc < DIM / 8; ++dc) {
            const int d0 = dc * 8;
            {
                const int row = t >> 1;
                const int dsl = (t & 1) * 4;
                const float4 xv = *(const float4*)(X + (size_t)(rowbase + row) * DIM + d0 + dsl);
                Xs[dsl + 0][row] = xv.x; Xs[dsl + 1][row] = xv.y;
                Xs[dsl + 2][row] = xv.z; Xs[dsl + 3][row] = xv.w;
            }
            {
                const int dr = t >> 5;
                const int c4 = (t & 31) * 4;
                const float4 ev = *(const float4*)(E + (size_t)(d0 + dr) * K_CODES + kbase + c4);
                *(float4*)&Es[dr][c4] = ev;
            }
            __syncthreads();
#pragma unroll
            for (int d = 0; d < 8; ++d) {
                float xr[8], er[8];
                *(float4*)&xr[0] = *(const float4*)&Xs[d][ty * 8];
                *(float4*)&xr[4] = *(const float4*)&Xs[d][ty * 8 + 4];
                *(float4*)&er[0] = *(const float4*)&Es[d][tx * 8];
                *(float4*)&er[4] = *(const float4*)&Es[d][tx * 8 + 4];
#pragma unroll
                for (int i = 0; i < 8; ++i)
#pragma unroll
                    for (int j = 0; j < 8; ++j)
                        acc[i][j] = fmaf(xr[i], er[j], acc[i][j]);
            }
            __syncthreads();
        }
        float eq[8];
        *(float4*)&eq[0] = *(const float4*)(esq + kbase + tx * 8);
        *(float4*)&eq[4] = *(const float4*)(esq + kbase + tx * 8 + 4);
#pragma unroll
        for (int i = 0; i < 8; ++i)
#pragma unroll
            for (int j = 0; j < 8; ++j) {
                const float dist = fmaf(-2.f, acc[i][j], eq[j]);
                if (dist < minv[i]) { minv[i] = dist; mini[i] = kbase + tx * 8 + j; }
            }
    }
#pragma unroll
    for (int i = 0; i < 8; ++i) {
        float v = minv[i];
        int   id = mini[i];
#pragma unroll
        for (int m = 8; m >= 1; m >>= 1) {
            const float v2 = __shfl_xor(v, m, 64);
            const int   i2 = __shfl_xor(id, m, 64);
            if (v2 < v || (v2 == v && i2 < id)) { v = v2; id = i2; }
        }
        if (tx == 0) {
            const int row = rowbase + ty * 8 + i;
            candv[row * 4 + ks] = v;
            candi[row * 4 + ks] = id;
        }
    }
}

__global__ void gather_loss(const float* __restrict__ X, const float* __restrict__ E,
                            const float* __restrict__ candv, const int* __restrict__ candi,
                            float* __restrict__ out, float* __restrict__ partials,
                            int nks) {
    const int w = threadIdx.x >> 6;
    const int l = threadIdx.x & 63;
    const int rowbase = blockIdx.x * (N_ROWS / GATHER_BLOCKS);
    float lsum = 0.f;

    for (int rr = w; rr < N_ROWS / GATHER_BLOCKS; rr += 4) {
        const int row = rowbase + rr;
        float bv = candv[row * nks];
        int   bi = candi[row * nks];
        for (int s = 1; s < nks; ++s) {
            const float v = candv[row * nks + s];
            const int  id = candi[row * nks + s];
            if (v < bv || (v == bv && id < bi)) { bv = v; bi = id; }
        }
        const float4 x = *(const float4*)(X + (size_t)row * DIM + l * 4);
        const float q0 = E[(size_t)(l * 4 + 0) * K_CODES + bi];
        const float q1 = E[(size_t)(l * 4 + 1) * K_CODES + bi];
        const float q2 = E[(size_t)(l * 4 + 2) * K_CODES + bi];
        const float q3 = E[(size_t)(l * 4 + 3) * K_CODES + bi];
        float4 q; q.x = q0; q.y = q1; q.z = q2; q.w = q3;
        *(float4*)(out + (size_t)row * DIM + l * 4) = q;
        const float d0 = x.x - q0, d1 = x.y - q1, d2 = x.z - q2, d3 = x.w - q3;
        lsum += d0 * d0 + d1 * d1 + d2 * d2 + d3 * d3;
    }
#pragma unroll
    for (int m = 32; m >= 1; m >>= 1) lsum += __shfl_xor(lsum, m, 64);
    __shared__ float ws4[4];
    if (l == 0) ws4[w] = lsum;
    __syncthreads();
    if (threadIdx.x == 0) partials[blockIdx.x] = (ws4[0] + ws4[1]) + (ws4[2] + ws4[3]);
}

__global__ void finalize(const float* __restrict__ partials, float* __restrict__ out_loss,
                         int npart) {
    __shared__ double s[256];
    double a = 0.0;
    for (int i = threadIdx.x; i < npart; i += 256) a += (double)partials[i];
    s[threadIdx.x] = a;
    __syncthreads();
    for (int st = 128; st > 0; st >>= 1) {
        if (threadIdx.x < st) s[threadIdx.x] += s[threadIdx.x + st];
        __syncthreads();
    }
    if (threadIdx.x == 0)
        out_loss[0] = (float)(1.25 * s[0] / (double)(N_ROWS * DIM));
}

extern "C" void kernel_launch(void* const* d_in, const int* in_sizes, int n_in,
                              void* d_out, int out_size, void* d_ws, size_t ws_size,
                              hipStream_t stream) {
    const float* X = (const float*)d_in[0];
    const float* E = (const float*)d_in[1];
    float* out = (float*)d_out;

    if (ws_size >= (size_t)WS_NEEDED) {
        // ---------------- MFMA path ----------------
        ushort_t* Ehi      = (ushort_t*)((char*)d_ws + 0);
        ushort_t* Elo      = (ushort_t*)((char*)d_ws + 2097152);
        float*    Et       = (float*)   ((char*)d_ws + 0);        // after dist_mfma
        int*      cand     = (int*)     ((char*)d_ws + 4194304);  // 512 KB
        float*    esq      = (float*)   ((char*)d_ws + 6291456);
        float*    partials = (float*)   ((char*)d_ws + 6438912);
        ushort_t* Xh       = (ushort_t*)d_out;                    // 16.78 MB
        ushort_t* Xl       = Xh + (size_t)N_ROWS * DIM;           // 16.78 MB

        prep_x<<<(N_ROWS * DIM / 4) / 256, 256, 0, stream>>>(X, Xh, Xl);
        prep_e<<<dim3(K_CODES / 64, DIM / 64), 256, 0, stream>>>(E, Ehi, Elo);
        esq_kernel<<<K_CODES / 16, 256, 0, stream>>>(E, esq);
        dist_mfma<<<dim3(NKS, N_ROWS / 128), 256, 0, stream>>>(
            Xh, Xl, Ehi, Elo, esq, cand);
        prep_et<<<dim3(K_CODES / 64, DIM / 64), 256, 0, stream>>>(E, Et);
        refine_gather<<<RG_BLOCKS, 256, 0, stream>>>(X, Et, cand, out, partials);
        finalize<<<1, 256, 0, stream>>>(partials, out + (size_t)N_ROWS * DIM, RG_BLOCKS);
    } else {
        // ---------------- fallback: round-1 fp32 path (needs ~1.07 MB) -----
        float* esq      = (float*)((char*)d_ws + 0);
        float* candv    = (float*)((char*)d_ws + 16384);
        int*   candi    = (int*)  ((char*)d_ws + 540672);
        float* partials = (float*)((char*)d_ws + 1064960);

        esq_kernel<<<K_CODES / 16, 256, 0, stream>>>(E, esq);
        dist_fp32<<<dim3(N_ROWS / 128, 4), 256, 0, stream>>>(X, E, esq, candv, candi);
        gather_loss<<<GATHER_BLOCKS, 256, 0, stream>>>(X, E, candv, candi, out,
                                                       partials, 4);
        finalize<<<1, 256, 0, stream>>>(partials, out + (size_t)N_ROWS * DIM,
                                        GATHER_BLOCKS);
    }
}

// Round 17
// 281.652 us; speedup vs baseline: 2.3845x; 1.0670x over previous
//
#include <hip/hip_runtime.h>

// Vector Quantizer, MFMA split-bf16 path + exact fp32 refine (row-major Et).
// inputs  d_in[0]: float32 X [32768, 256]
// emb     d_in[1]: float32 E [256, 4096]
// d_out: [8388608 floats e_k] + [1 float loss]
//
// dot(x,e) ~ 3 bf16 MFMAs: xh*eh + xh*el + xl*eh (fp32 accum).
// dist_mfma v18 = v17 (NKS=2, A-register-file, B-only LDS dbuf, top-2 state
// in LDS, pinned 256-unified-reg budget -> zero spill) plus:
//  - s_setprio(1) around the MFMA burst (2 independent blocks/CU = the
//    phase-diverse regime where setprio measured +4-7%)
//  - per-ct esq loads hoisted to ct start (L2 latency hides under 8 kts)
// Top-2 per (row, 2048-col strip) -> 4 cands/row -> exact fp32 refine.
// Xh/Xl bf16 (row-major) staged in d_out (overwritten by gather later).

typedef unsigned short ushort_t;
typedef unsigned int uint_t;
typedef __attribute__((ext_vector_type(8))) short bf16x8;
typedef __attribute__((ext_vector_type(4))) float f32x4;

#define N_ROWS 32768
#define DIM 256
#define K_CODES 4096
#define NKS 2            // col strips (2048 cols each)
#define GATHER_BLOCKS 512
#define RG_BLOCKS (N_ROWS / 32)   // fused refine+gather: 32 rows/block

// ---- ws layout (mfma path), bytes ----
// Ehi      [0,       2097152)   bf16 [4096][256]   (dead after dist_mfma)
// Elo      [2097152, 4194304)                      (dead after dist_mfma)
// Et       [0,       4194304)   fp32 [4096][256]   (built after dist_mfma)
// cand     [4194304, 4718592)   int [32768][2 strips][2]
// esq      [6291456, 6307840)   float[4096]
// partials [6438912, 6443008)   float[1024]
#define WS_NEEDED (8u * 1024u * 1024u)

__device__ __forceinline__ unsigned short bf16_rne(float x) {
    unsigned u = __builtin_bit_cast(unsigned, x);
    unsigned r = u + 0x7fffu + ((u >> 16) & 1u);
    return (unsigned short)(r >> 16);
}
__device__ __forceinline__ float bf16_f(unsigned short h) {
    unsigned u = ((unsigned)h) << 16;
    return __builtin_bit_cast(float, u);
}
// total-order "better": smaller dist, tie -> smaller index
__device__ __forceinline__ bool better(float d, int c, float v, int i) {
    return (d < v) || (d == v && c < i);
}

// ---------------- prep: X -> Xh/Xl (bf16 split, row-major), into d_out -----
__global__ void prep_x(const float* __restrict__ X, ushort_t* __restrict__ Xh,
                       ushort_t* __restrict__ Xl) {
    int i = blockIdx.x * 256 + threadIdx.x;   // float4 index
    float4 v = ((const float4*)X)[i];
    ushort4 h, l;
    h.x = bf16_rne(v.x); l.x = bf16_rne(v.x - bf16_f(h.x));
    h.y = bf16_rne(v.y); l.y = bf16_rne(v.y - bf16_f(h.y));
    h.z = bf16_rne(v.z); l.z = bf16_rne(v.z - bf16_f(h.z));
    h.w = bf16_rne(v.w); l.w = bf16_rne(v.w - bf16_f(h.w));
    ((ushort4*)Xh)[i] = h;
    ((ushort4*)Xl)[i] = l;
}

// ------------- prep: E [256][4096] -> E^T hi/lo [4096][256] bf16 -----------
__global__ void prep_e(const float* __restrict__ E, ushort_t* __restrict__ Ehi,
                       ushort_t* __restrict__ Elo) {
    __shared__ ushort_t sh[64][66];
    __shared__ ushort_t sl[64][66];
    const int t = threadIdx.x;
    const int kbase = blockIdx.x * 64;
    const int dbase = blockIdx.y * 64;
#pragma unroll
    for (int i = 0; i < 16; ++i) {
        int lin = i * 256 + t;
        int dl = lin >> 6, kl = lin & 63;
        float v = E[(size_t)(dbase + dl) * K_CODES + kbase + kl];
        unsigned short h = bf16_rne(v);
        unsigned short l = bf16_rne(v - bf16_f(h));
        sh[kl][dl] = h;
        sl[kl][dl] = l;
    }
    __syncthreads();
#pragma unroll
    for (int i = 0; i < 8; ++i) {
        int lin = i * 256 + t;
        int kl = lin >> 5, d2 = (lin & 31) * 2;
        uint_t vh = (uint_t)sh[kl][d2] | ((uint_t)sh[kl][d2 + 1] << 16);
        uint_t vl = (uint_t)sl[kl][d2] | ((uint_t)sl[kl][d2 + 1] << 16);
        *(uint_t*)&Ehi[(size_t)(kbase + kl) * DIM + dbase + d2] = vh;
        *(uint_t*)&Elo[(size_t)(kbase + kl) * DIM + dbase + d2] = vl;
    }
}

// ------------- prep: E [256][4096] -> Et fp32 [4096][256] (exact) ----------
__global__ void prep_et(const float* __restrict__ E, float* __restrict__ Et) {
    __shared__ float s[64][65];
    const int t = threadIdx.x;
    const int kbase = blockIdx.x * 64;
    const int dbase = blockIdx.y * 64;
#pragma unroll
    for (int i = 0; i < 16; ++i) {
        int lin = i * 256 + t;
        int dl = lin >> 6, kl = lin & 63;
        s[kl][dl] = E[(size_t)(dbase + dl) * K_CODES + kbase + kl];
    }
    __syncthreads();
#pragma unroll
    for (int i = 0; i < 16; ++i) {
        int lin = i * 256 + t;
        int kl = lin >> 6, dl = lin & 63;
        Et[(size_t)(kbase + kl) * DIM + dbase + dl] = s[kl][dl];
    }
}

// ---------------- esq[k] = sum_d E[d][k]^2 (fp32, from original E) ---------
__global__ void esq_kernel(const float* __restrict__ E, float* __restrict__ esq) {
    __shared__ float red[16][17];
    int t = threadIdx.x;
    int kk = t & 15, dg = t >> 4;
    int k = blockIdx.x * 16 + kk;
    float a = 0.f;
#pragma unroll
    for (int it = 0; it < 16; ++it) {
        float e = E[(dg + it * 16) * K_CODES + k];
        a = fmaf(e, e, a);
    }
    red[dg][kk] = a;
    __syncthreads();
    if (t < 16) {
        float s = 0.f;
#pragma unroll
        for (int g = 0; g < 16; ++g) s += red[g][t];
        esq[blockIdx.x * 16 + t] = s;
    }
}

// ---------------- main: MFMA distance + per-strip top-2 (v18) --------------
// grid (NKS=2, 256) flattened+swizzled: 512 = 8 xcd x 64; xcd owns 32
// contiguous rowblocks x both strips; all 512 blocks co-resident (2/CU).
// 256 threads = 4 waves; wave w owns rows [w*32, w*32+32) (2 m-blocks) x
// all 128 cols of each ct tile. A (X hi/lo) fragments in registers; B (E^T
// hi/lo) staged to LDS double-buffered, stage issued before compute; top-2
// state in LDS ([slot][tid], conflict-free). setprio(1) around MFMA burst.
__global__
__attribute__((amdgpu_flat_work_group_size(256, 256)))
__attribute__((amdgpu_waves_per_eu(2, 2)))
__attribute__((amdgpu_num_vgpr(256)))
void dist_mfma(
    const ushort_t* __restrict__ Xh, const ushort_t* __restrict__ Xl,
    const ushort_t* __restrict__ Ehi, const ushort_t* __restrict__ Elo,
    const float* __restrict__ esq, int* __restrict__ cand) {
    __shared__ short lds[16384];        // 32 KB B staging (2 x 16 KB bufs)
    __shared__ uint_t s_state[32][256]; // 32 KB top-2 state:
                                        // [0..7]=v1 [8..15]=v2 [16..23]=i1 [24..31]=i2
    const int t = threadIdx.x;
    const int l = t & 63, w = t >> 6;
    const int l15 = l & 15, lg = l >> 4;

    // bijective XCD swizzle (512 blocks = 8 XCD x 64)
    const int wgid = blockIdx.x + blockIdx.y * NKS;
    const int xcd = wgid & 7, pos = wgid >> 3;
    const int ks = pos & 1;
    const int rowbase = (xcd * 32 + (pos >> 1)) * 128;

    const int n0 = 2 * w, n1 = 2 * w + 1;   // B n-blocks staged by this wave

#define GLDS(srcp, dstoff)                                                      \
    __builtin_amdgcn_global_load_lds(                                           \
        (const __attribute__((address_space(1))) void*)(srcp),                  \
        (__attribute__((address_space(3))) void*)&lds[dstoff], 16, 0, 0)
#define STAGE(pbuf, cbase, ktv) do {                                            \
    const uint_t o0 = (uint_t)((cbase) + n0 * 16 + l15) * DIM + (ktv) * 32 + lg * 8; \
    const uint_t o1 = (uint_t)((cbase) + n1 * 16 + l15) * DIM + (ktv) * 32 + lg * 8; \
    GLDS(Ehi + o0, (pbuf) * 8192 + n0 * 512);                                   \
    GLDS(Ehi + o1, (pbuf) * 8192 + n1 * 512);                                   \
    GLDS(Elo + o0, (pbuf) * 8192 + 4096 + n0 * 512);                            \
    GLDS(Elo + o1, (pbuf) * 8192 + 4096 + n1 * 512);                            \
} while (0)

    // issue first B-stage before the A prologue so DMA overlaps A latency
    STAGE(0, ks * 2048, 0);

    // ---- A prologue: 2 m-blocks x 8 kt, hi+lo fragments -> 128 VGPRs
    bf16x8 ah[2][8], al[2][8];
#pragma unroll
    for (int m = 0; m < 2; ++m) {
        const uint_t base = (uint_t)(rowbase + w * 32 + m * 16 + l15) * DIM + lg * 8;
#pragma unroll
        for (int kt = 0; kt < 8; ++kt) {
            ah[m][kt] = *(const bf16x8*)(Xh + base + kt * 32);
            al[m][kt] = *(const bf16x8*)(Xl + base + kt * 32);
        }
    }

    // init top-2 state in LDS (thread-private slots, no barrier needed)
#pragma unroll
    for (int s = 0; s < 8; ++s) {
        s_state[s][t]      = __builtin_bit_cast(uint_t, 3.4e38f);
        s_state[8 + s][t]  = __builtin_bit_cast(uint_t, 3.4e38f);
        s_state[16 + s][t] = 0x7fffffffu;
        s_state[24 + s][t] = 0x7fffffffu;
    }

    __syncthreads();

#pragma unroll 1
    for (int ct = 0; ct < 16; ++ct) {
        const int cb = ks * 2048 + ct * 128;

        // hoisted per-ct esq loads: L2 latency hides under the 8-kt MFMA window
        float eq[8];
#pragma unroll
        for (int n = 0; n < 8; ++n) eq[n] = esq[cb + n * 16 + l15];

        f32x4 acc[2][8];
#pragma unroll
        for (int m = 0; m < 2; ++m)
#pragma unroll
            for (int n = 0; n < 8; ++n) acc[m][n] = (f32x4){0.f, 0.f, 0.f, 0.f};

#pragma unroll
        for (int kt = 0; kt < 8; ++kt) {
            const int cur = kt & 1;
            // stage next (ct,kt) into the other buffer BEFORE compute
            if (kt < 7) {
                STAGE(cur ^ 1, cb, kt + 1);
            } else if (ct < 15) {
                STAGE(cur ^ 1, cb + 128, 0);
            }
            // compute current kt from buf[cur] (A from registers)
            __builtin_amdgcn_s_setprio(1);
#pragma unroll
            for (int n = 0; n < 8; ++n) {
                const bf16x8 bh = *(const bf16x8*)&lds[cur * 8192 + n * 512 + l * 8];
                const bf16x8 bl = *(const bf16x8*)&lds[cur * 8192 + 4096 + n * 512 + l * 8];
#pragma unroll
                for (int m = 0; m < 2; ++m) {
                    acc[m][n] = __builtin_amdgcn_mfma_f32_16x16x32_bf16(
                        ah[m][kt], bh, acc[m][n], 0, 0, 0);
                    acc[m][n] = __builtin_amdgcn_mfma_f32_16x16x32_bf16(
                        ah[m][kt], bl, acc[m][n], 0, 0, 0);
                    acc[m][n] = __builtin_amdgcn_mfma_f32_16x16x32_bf16(
                        al[m][kt], bh, acc[m][n], 0, 0, 0);
                }
            }
            __builtin_amdgcn_s_setprio(0);
            // barrier: drains vmcnt (next stage) + lgkm
            __syncthreads();
        }

        // epilogue: dist = esq - 2*dot, top-2 update per (m,q); state in LDS
#pragma unroll
        for (int m = 0; m < 2; ++m)
#pragma unroll
            for (int q = 0; q < 4; ++q) {
                const int s = m * 4 + q;
                float v1 = __builtin_bit_cast(float, s_state[s][t]);
                float v2 = __builtin_bit_cast(float, s_state[8 + s][t]);
                int   i1 = (int)s_state[16 + s][t];
                int   i2 = (int)s_state[24 + s][t];
#pragma unroll
                for (int n = 0; n < 8; ++n) {
                    const int col = cb + n * 16 + l15;
                    const float d = fmaf(-2.f, acc[m][n][q], eq[n]);
                    if (better(d, col, v1, i1)) {
                        v2 = v1; i2 = i1;
                        v1 = d;  i1 = col;
                    } else if (better(d, col, v2, i2)) {
                        v2 = d; i2 = col;
                    }
                }
                s_state[s][t]      = __builtin_bit_cast(uint_t, v1);
                s_state[8 + s][t]  = __builtin_bit_cast(uint_t, v2);
                s_state[16 + s][t] = (uint_t)i1;
                s_state[24 + s][t] = (uint_t)i2;
            }
    }
#undef STAGE
#undef GLDS

    // cross-lane top-2 merge over the 16 col-lanes (indices all distinct)
#pragma unroll
    for (int m = 0; m < 2; ++m)
#pragma unroll
        for (int q = 0; q < 4; ++q) {
            const int s = m * 4 + q;
            float a1 = __builtin_bit_cast(float, s_state[s][t]);
            float a2 = __builtin_bit_cast(float, s_state[8 + s][t]);
            int   b1 = (int)s_state[16 + s][t];
            int   b2 = (int)s_state[24 + s][t];
#pragma unroll
            for (int msk = 8; msk >= 1; msk >>= 1) {
                const float c1 = __shfl_xor(a1, msk, 64);
                const int   d1 = __shfl_xor(b1, msk, 64);
                const float c2 = __shfl_xor(a2, msk, 64);
                const int   d2 = __shfl_xor(b2, msk, 64);
                if (better(c1, d1, a1, b1)) {
                    if (better(a1, b1, c2, d2)) { a2 = a1; b2 = b1; }
                    else                        { a2 = c2; b2 = d2; }
                    a1 = c1; b1 = d1;
                } else {
                    if (better(c1, d1, a2, b2)) { a2 = c1; b2 = d1; }
                }
            }
            if (l15 == 0) {
                const int row = rowbase + w * 32 + m * 16 + lg * 4 + q;
                cand[(row * NKS + ks) * 2 + 0] = b1;
                cand[(row * NKS + ks) * 2 + 1] = b2;
            }
        }
}

// ------- fused refine (exact fp32 over 4 cands) + gather + loss ------------
// 4 waves/block, 8 rows each. Refine: lane = (cand 0..3) x (dim-group 0..15
// of 16 dims); xor-4/8/16/32 sum, then xor-2..1 argmin -> ALL lanes agree.
__global__ void refine_gather(const float* __restrict__ X, const float* __restrict__ Et,
                              const int* __restrict__ cand,
                              float* __restrict__ out, float* __restrict__ partials) {
    const int w = threadIdx.x >> 6, l = threadIdx.x & 63;
    const int cs = l & 3, dg = l >> 2;
    const int row0 = blockIdx.x * 32 + w * 8;
    float lsum = 0.f;

#pragma unroll 1
    for (int rr = 0; rr < 8; ++rr) {
        const int row = row0 + rr;
        const int c = cand[row * 4 + cs];
        const float4* ep = (const float4*)(Et + (size_t)c * DIM + dg * 16);
        const float4* xp = (const float4*)(X + (size_t)row * DIM + dg * 16);
        float p = 0.f;
#pragma unroll
        for (int j = 0; j < 4; ++j) {
            const float4 e = ep[j];
            const float4 x = xp[j];
            p = fmaf(e.x, fmaf(-2.f, x.x, e.x), p);
            p = fmaf(e.y, fmaf(-2.f, x.y, e.y), p);
            p = fmaf(e.z, fmaf(-2.f, x.z, e.z), p);
            p = fmaf(e.w, fmaf(-2.f, x.w, e.w), p);
        }
        p += __shfl_xor(p, 4, 64);
        p += __shfl_xor(p, 8, 64);
        p += __shfl_xor(p, 16, 64);
        p += __shfl_xor(p, 32, 64);
        float v = p; int id = c;
#pragma unroll
        for (int m = 2; m >= 1; m >>= 1) {
            const float v2 = __shfl_xor(v, m, 64);
            const int  id2 = __shfl_xor(id, m, 64);
            if (v2 < v || (v2 == v && id2 < id)) { v = v2; id = id2; }
        }
        // gather + loss (all lanes agree on id)
        const float4 x = *(const float4*)(X + (size_t)row * DIM + l * 4);
        const float4 q = *(const float4*)(Et + (size_t)id * DIM + l * 4);
        *(float4*)(out + (size_t)row * DIM + l * 4) = q;
        const float d0 = x.x - q.x, d1 = x.y - q.y, d2 = x.z - q.z, d3 = x.w - q.w;
        lsum += d0 * d0 + d1 * d1 + d2 * d2 + d3 * d3;
    }
#pragma unroll
    for (int m = 32; m >= 1; m >>= 1) lsum += __shfl_xor(lsum, m, 64);
    __shared__ float ws4[4];
    if (l == 0) ws4[w] = lsum;
    __syncthreads();
    if (threadIdx.x == 0) partials[blockIdx.x] = (ws4[0] + ws4[1]) + (ws4[2] + ws4[3]);
}

// -------- fallback fp32 dist (round-1 proven path, used if ws too small) ---
__global__ void dist_fp32(const float* __restrict__ X, const float* __restrict__ E,
                          const float* __restrict__ esq,
                          float* __restrict__ candv, int* __restrict__ candi) {
    __shared__ float Xs[8][128];
    __shared__ float Es[8][128];
    const int t = threadIdx.x;
    const int tx = t & 15;
    const int ty = t >> 4;
    const int rowbase = blockIdx.x * 128;
    const int ks = blockIdx.y;

    float minv[8];
    int   mini[8];
#pragma unroll
    for (int i = 0; i < 8; ++i) { minv[i] = 3.4e38f; mini[i] = 0; }

    for (int kt = 0; kt < 8; ++kt) {
        const int kbase = ks * 1024 + kt * 128;
        float acc[8][8];
#pragma unroll
        for (int i = 0; i < 8; ++i)
#pragma unroll
            for (int j = 0; j < 8; ++j) acc[i][j] = 0.f;

        for (int dc = 0; dc < DIM / 8; ++dc) {
            const int d0 = dc * 8;
            {
                const int row = t >> 1;
                const int dsl = (t & 1) * 4;
                const float4 xv = *(const float4*)(X + (size_t)(rowbase + row) * DIM + d0 + dsl);
                Xs[dsl + 0][row] = xv.x; Xs[dsl + 1][row] = xv.y;
                Xs[dsl + 2][row] = xv.z; Xs[dsl + 3][row] = xv.w;
            }
            {
                const int dr = t >> 5;
                const int c4 = (t & 31) * 4;
                const float4 ev = *(const float4*)(E + (size_t)(d0 + dr) * K_CODES + kbase + c4);
                *(float4*)&Es[dr][c4] = ev;
            }
            __syncthreads();
#pragma unroll
            for (int d = 0; d < 8; ++d) {
                float xr[8], er[8];
                *(float4*)&xr[0] = *(const float4*)&Xs[d][ty * 8];
                *(float4*)&xr[4] = *(const float4*)&Xs[d][ty * 8 + 4];
                *(float4*)&er[0] = *(const float4*)&Es[d][tx * 8];
                *(float4*)&er[4] = *(const float4*)&Es[d][tx * 8 + 4];
#pragma unroll
                for (int i = 0; i < 8; ++i)
#pragma unroll
                    for (int j = 0; j < 8; ++j)
                        acc[i][j] = fmaf(xr[i], er[j], acc[i][j]);
            }
            __syncthreads();
        }
        float eq[8];
        *(float4*)&eq[0] = *(const float4*)(esq + kbase + tx * 8);
        *(float4*)&eq[4] = *(const float4*)(esq + kbase + tx * 8 + 4);
#pragma unroll
        for (int i = 0; i < 8; ++i)
#pragma unroll
            for (int j = 0; j < 8; ++j) {
                const float dist = fmaf(-2.f, acc[i][j], eq[j]);
                if (dist < minv[i]) { minv[i] = dist; mini[i] = kbase + tx * 8 + j; }
            }
    }
#pragma unroll
    for (int i = 0; i < 8; ++i) {
        float v = minv[i];
        int   id = mini[i];
#pragma unroll
        for (int m = 8; m >= 1; m >>= 1) {
            const float v2 = __shfl_xor(v, m, 64);
            const int   i2 = __shfl_xor(id, m, 64);
            if (v2 < v || (v2 == v && i2 < id)) { v = v2; id = i2; }
        }
        if (tx == 0) {
            const int row = rowbase + ty * 8 + i;
            candv[row * 4 + ks] = v;
            candi[row * 4 + ks] = id;
        }
    }
}

__global__ void gather_loss(const float* __restrict__ X, const float* __restrict__ E,
                            const float* __restrict__ candv, const int* __restrict__ candi,
                            float* __restrict__ out, float* __restrict__ partials,
                            int nks) {
    const int w = threadIdx.x >> 6;
    const int l = threadIdx.x & 63;
    const int rowbase = blockIdx.x * (N_ROWS / GATHER_BLOCKS);
    float lsum = 0.f;

    for (int rr = w; rr < N_ROWS / GATHER_BLOCKS; rr += 4) {
        const int row = rowbase + rr;
        float bv = candv[row * nks];
        int   bi = candi[row * nks];
        for (int s = 1; s < nks; ++s) {
            const float v = candv[row * nks + s];
            const int  id = candi[row * nks + s];
            if (v < bv || (v == bv && id < bi)) { bv = v; bi = id; }
        }
        const float4 x = *(const float4*)(X + (size_t)row * DIM + l * 4);
        const float q0 = E[(size_t)(l * 4 + 0) * K_CODES + bi];
        const float q1 = E[(size_t)(l * 4 + 1) * K_CODES + bi];
        const float q2 = E[(size_t)(l * 4 + 2) * K_CODES + bi];
        const float q3 = E[(size_t)(l * 4 + 3) * K_CODES + bi];
        float4 q; q.x = q0; q.y = q1; q.z = q2; q.w = q3;
        *(float4*)(out + (size_t)row * DIM + l * 4) = q;
        const float d0 = x.x - q0, d1 = x.y - q1, d2 = x.z - q2, d3 = x.w - q3;
        lsum += d0 * d0 + d1 * d1 + d2 * d2 + d3 * d3;
    }
#pragma unroll
    for (int m = 32; m >= 1; m >>= 1) lsum += __shfl_xor(lsum, m, 64);
    __shared__ float ws4[4];
    if (l == 0) ws4[w] = lsum;
    __syncthreads();
    if (threadIdx.x == 0) partials[blockIdx.x] = (ws4[0] + ws4[1]) + (ws4[2] + ws4[3]);
}

__global__ void finalize(const float* __restrict__ partials, float* __restrict__ out_loss,
                         int npart) {
    __shared__ double s[256];
    double a = 0.0;
    for (int i = threadIdx.x; i < npart; i += 256) a += (double)partials[i];
    s[threadIdx.x] = a;
    __syncthreads();
    for (int st = 128; st > 0; st >>= 1) {
        if (threadIdx.x < st) s[threadIdx.x] += s[threadIdx.x + st];
        __syncthreads();
    }
    if (threadIdx.x == 0)
        out_loss[0] = (float)(1.25 * s[0] / (double)(N_ROWS * DIM));
}

extern "C" void kernel_launch(void* const* d_in, const int* in_sizes, int n_in,
                              void* d_out, int out_size, void* d_ws, size_t ws_size,
                              hipStream_t stream) {
    const float* X = (const float*)d_in[0];
    const float* E = (const float*)d_in[1];
    float* out = (float*)d_out;

    if (ws_size >= (size_t)WS_NEEDED) {
        // ---------------- MFMA path ----------------
        ushort_t* Ehi      = (ushort_t*)((char*)d_ws + 0);
        ushort_t* Elo      = (ushort_t*)((char*)d_ws + 2097152);
        float*    Et       = (float*)   ((char*)d_ws + 0);        // after dist_mfma
        int*      cand     = (int*)     ((char*)d_ws + 4194304);  // 512 KB
        float*    esq      = (float*)   ((char*)d_ws + 6291456);
        float*    partials = (float*)   ((char*)d_ws + 6438912);
        ushort_t* Xh       = (ushort_t*)d_out;                    // 16.78 MB
        ushort_t* Xl       = Xh + (size_t)N_ROWS * DIM;           // 16.78 MB

        prep_x<<<(N_ROWS * DIM / 4) / 256, 256, 0, stream>>>(X, Xh, Xl);
        prep_e<<<dim3(K_CODES / 64, DIM / 64), 256, 0, stream>>>(E, Ehi, Elo);
        esq_kernel<<<K_CODES / 16, 256, 0, stream>>>(E, esq);
        dist_mfma<<<dim3(NKS, N_ROWS / 128), 256, 0, stream>>>(
            Xh, Xl, Ehi, Elo, esq, cand);
        prep_et<<<dim3(K_CODES / 64, DIM / 64), 256, 0, stream>>>(E, Et);
        refine_gather<<<RG_BLOCKS, 256, 0, stream>>>(X, Et, cand, out, partials);
        finalize<<<1, 256, 0, stream>>>(partials, out + (size_t)N_ROWS * DIM, RG_BLOCKS);
    } else {
        // ---------------- fallback: round-1 fp32 path (needs ~1.07 MB) -----
        float* esq      = (float*)((char*)d_ws + 0);
        float* candv    = (float*)((char*)d_ws + 16384);
        int*   candi    = (int*)  ((char*)d_ws + 540672);
        float* partials = (float*)((char*)d_ws + 1064960);

        esq_kernel<<<K_CODES / 16, 256, 0, stream>>>(E, esq);
        dist_fp32<<<dim3(N_ROWS / 128, 4), 256, 0, stream>>>(X, E, esq, candv, candi);
        gather_loss<<<GATHER_BLOCKS, 256, 0, stream>>>(X, E, candv, candi, out,
                                                       partials, 4);
        finalize<<<1, 256, 0, stream>>>(partials, out + (size_t)N_ROWS * DIM,
                                        GATHER_BLOCKS);
    }
}